// Round 1
// baseline (318.031 us; speedup 1.0000x reference)
//
#include <hip/hip_runtime.h>
#include <stdint.h>

// ---------- types ----------
typedef __attribute__((ext_vector_type(8))) __bf16 bf16x8;
typedef __attribute__((ext_vector_type(4))) float f32x4;
typedef __attribute__((ext_vector_type(8))) unsigned short ushort8;

// ---------- helpers ----------
__device__ __forceinline__ float bf2f(unsigned short u){
  union { unsigned int i; float f; } v; v.i = ((unsigned int)u) << 16; return v.f;
}
__device__ __forceinline__ unsigned short f2bf(float f){
  union { float f; unsigned int i; } v; v.f = f;
  unsigned int r = v.i + 0x7fffu + ((v.i >> 16) & 1u);   // RNE
  return (unsigned short)(r >> 16);
}
__device__ __forceinline__ void gload16(const void* g, void* l){
  __builtin_amdgcn_global_load_lds((__attribute__((address_space(1))) void*)(g),
                                   (__attribute__((address_space(3))) void*)(l),
                                   16, 0, 0);
}

// ---------- constants ----------
#define SEQ   2048
#define DM    1024
#define NH    16
#define DK    64
#define BATCH 4
#define MTOT  (BATCH*SEQ)          // 8192
#define NX    (MTOT*DM)            // 8388608 elements in x
#define NW    (DM*DM)              // 1048576 per weight

// ============================================================
// sin/cos table: tab[s*32+i] = {cos, sin} of pos[s]*theta^(-2i/64)
// ============================================================
__global__ __launch_bounds__(256) void k_tables(const int* __restrict__ pos,
                                                float* __restrict__ tab)
{
  const int idx = blockIdx.x * 256 + threadIdx.x;    // 65536 total
  const int s = idx >> 5, i = idx & 31;
  // inv_freq = 10000^(-i/32) = exp(-ln(10000)/32 * i)
  const float inv = __expf(-0.28782313662425575f * (float)i);
  const float a = (float)pos[s] * inv;
  tab[2*idx]   = cosf(a);
  tab[2*idx+1] = sinf(a);
}

// ============================================================
// fp32 -> bf16 convert: x (8.4M) then Wq,Wk,Wv,Wo (1M each)
// ============================================================
__global__ __launch_bounds__(256) void k_convert(
    const float* __restrict__ x,  const float* __restrict__ wq,
    const float* __restrict__ wk, const float* __restrict__ wv,
    const float* __restrict__ wo,
    unsigned short* __restrict__ xb, unsigned short* __restrict__ wb)
{
  const long long tid = (long long)blockIdx.x * 256 + threadIdx.x;
  const long long e = tid * 4;
  const float* src; unsigned short* dst;
  if (e < NX) { src = x + e; dst = xb + e; }
  else {
    long long j = e - NX;
    int seg = (int)(j >> 20);            // /1048576
    long long off = j & 1048575;
    src = (seg==0?wq:seg==1?wk:seg==2?wv:wo) + off;
    dst = wb + (size_t)seg*NW + off;
  }
  float4 v = *(const float4*)src;
  unsigned long long pk =  (unsigned long long)f2bf(v.x)
                        | ((unsigned long long)f2bf(v.y) << 16)
                        | ((unsigned long long)f2bf(v.z) << 32)
                        | ((unsigned long long)f2bf(v.w) << 48);
  *(unsigned long long*)dst = pk;
}

// ============================================================
// NT GEMM: C[M=8192][N=1024] = A[M][K=1024] * W[N][K]^T  (bf16 MFMA)
// 128x128 tile, BK=32, 4 waves (2x2), m97-style global_load_lds staging.
// MODE 0: grid.z in {0,1,2} -> W{q,k,v}, write bf16 to [b][h][s][d]
// MODE 1: write fp32 to Dout [M][N]
// ============================================================
#define BK 32
#define NTK (DM/BK)   // 32

template<int MODE>
__global__ __launch_bounds__(256) void k_gemm(
    const unsigned short* __restrict__ A,
    const unsigned short* __restrict__ W0,
    const unsigned short* __restrict__ W1,
    const unsigned short* __restrict__ W2,
    unsigned short* __restrict__ D0,
    unsigned short* __restrict__ D1,
    unsigned short* __restrict__ D2,
    float* __restrict__ Dout)
{
  __shared__ __attribute__((aligned(16))) unsigned short As[2][128*BK];
  __shared__ __attribute__((aligned(16))) unsigned short Bs[2][128*BK];
  const int tid  = threadIdx.x;
  const int lane = tid & 63;
  const int wv   = tid >> 6;
  const int wm = wv >> 1, wn = wv & 1;
  const int m0 = blockIdx.x * 128;
  const int n0 = blockIdx.y * 128;

  const unsigned short* W;
  unsigned short* Dh = nullptr;
  if (MODE == 0) {
    const int z = blockIdx.z;
    W  = (z == 0) ? W0 : (z == 1) ? W1 : W2;
    Dh = (z == 0) ? D0 : (z == 1) ? D1 : D2;
  } else {
    W = W0;
  }

  f32x4 acc[4][4];
  #pragma unroll
  for (int i = 0; i < 4; ++i)
    #pragma unroll
    for (int j = 0; j < 4; ++j)
      acc[i][j] = (f32x4)0.0f;

  auto stage = [&](int buf, int t){
    const int k0 = t * BK;
    #pragma unroll
    for (int cc = 0; cc < 2; ++cc){
      const int f = cc*256 + tid;
      const int row = f >> 2, kc = f & 3;
      gload16(A + (size_t)(m0 + row)*DM + k0 + kc*8,
              (char*)&As[buf][0] + (cc*256 + wv*64)*16);
      gload16(W + (size_t)(n0 + row)*DM + k0 + kc*8,
              (char*)&Bs[buf][0] + (cc*256 + wv*64)*16);
    }
  };

  stage(0, 0);
  __syncthreads();
  int cur = 0;
  for (int t = 0; t < NTK; ++t){
    if (t + 1 < NTK) stage(cur ^ 1, t + 1);
    const char* Ab_ = (const char*)&As[cur][0];
    const char* Bb_ = (const char*)&Bs[cur][0];
    bf16x8 af[4], bfr[4];
    #pragma unroll
    for (int i = 0; i < 4; ++i){
      af[i]  = *(const bf16x8*)(Ab_ + (wm*64 + i*16 + (lane & 15))*64 + ((lane >> 4) << 4));
      bfr[i] = *(const bf16x8*)(Bb_ + (wn*64 + i*16 + (lane & 15))*64 + ((lane >> 4) << 4));
    }
    #pragma unroll
    for (int i = 0; i < 4; ++i)
      #pragma unroll
      for (int j = 0; j < 4; ++j)
        acc[i][j] = __builtin_amdgcn_mfma_f32_16x16x32_bf16(af[i], bfr[j], acc[i][j], 0, 0, 0);
    __syncthreads();
    cur ^= 1;
  }

  // epilogue: C row = (lane>>4)*4+r, col = lane&15 (verified m89/m91 layout)
  #pragma unroll
  for (int i = 0; i < 4; ++i)
    #pragma unroll
    for (int j = 0; j < 4; ++j)
      #pragma unroll
      for (int r = 0; r < 4; ++r){
        const int m = m0 + wm*64 + i*16 + ((lane >> 4) << 2) + r;
        const int n = n0 + wn*64 + j*16 + (lane & 15);
        if (MODE == 0){
          const int b = m >> 11, s = m & 2047, hh = n >> 6, d = n & 63;
          Dh[((size_t)((b*NH + hh)*SEQ + s))*DK + d] = f2bf(acc[i][j][r]);
        } else {
          Dout[(size_t)m * DM + n] = acc[i][j][r];
        }
      }
}

// ============================================================
// RoPE in place on Qh/Kh [bh][s][64]; Q pre-scaled by 1/8.
// blockIdx.y: 0 -> Q, 1 -> K. One thread per (even,odd) pair.
// ============================================================
__global__ __launch_bounds__(256) void k_rope(unsigned short* __restrict__ Qh,
                                              unsigned short* __restrict__ Kh,
                                              const float* __restrict__ tab)
{
  const int idx = blockIdx.x * 256 + threadIdx.x;   // 4194304 per tensor
  const int z = blockIdx.y;
  const int s = (idx >> 5) & (SEQ-1);
  const int i = idx & 31;
  unsigned int* p = (unsigned int*)(z ? Kh : Qh) + idx;  // pair index == uint index
  const float scale = z ? 1.0f : 0.125f;
  const unsigned int v = *p;
  const float xe = bf2f((unsigned short)(v & 0xffff));
  const float xo = bf2f((unsigned short)(v >> 16));
  const float c  = tab[2*(s*32+i)];
  const float sn = tab[2*(s*32+i)+1];
  const float oe = (c*xe - sn*xo) * scale;
  const float oo = (sn*xe + c*xo) * scale;
  *p = (unsigned int)f2bf(oe) | ((unsigned int)f2bf(oo) << 16);
}

// ============================================================
// V transpose: Vh [bh][s][64] -> Vt [bh][64][s]
// ============================================================
__global__ __launch_bounds__(256) void k_transpose(const unsigned short* __restrict__ Vh,
                                                   unsigned short* __restrict__ Vt)
{
  __shared__ unsigned short t[64][72];   // +8 pad
  const int bh = blockIdx.y;
  const int s0 = blockIdx.x * 64;
  const int tid = threadIdx.x;
  const int row = tid >> 2, ch = (tid & 3) * 16;
  const unsigned short* src = Vh + (size_t)bh*(SEQ*DK) + (size_t)(s0 + row)*DK + ch;
  *(ushort8*)&t[row][ch]     = *(const ushort8*)(src);
  *(ushort8*)&t[row][ch + 8] = *(const ushort8*)(src + 8);
  __syncthreads();
  ushort8 a, b;
  #pragma unroll
  for (int j = 0; j < 8; ++j) a[j] = t[ch + j][row];
  #pragma unroll
  for (int j = 0; j < 8; ++j) b[j] = t[ch + 8 + j][row];
  unsigned short* dst = Vt + (size_t)bh*(SEQ*DK) + (size_t)row*SEQ + s0 + ch;
  *(ushort8*)dst       = a;
  *(ushort8*)(dst + 8) = b;
}

// ============================================================
// Causal flash attention. Block = 4 waves; wave w owns 32 q-rows.
// K tile 64x64 and Vt tile 64x64 staged via global_load_lds with
// pre-swizzled SOURCE (XOR ((row&7)<<4)) + swizzled ds_read (rule #21).
// P round-trips through per-wave swizzled LDS (C-layout -> A-layout).
// Q is pre-scaled by 1/8; out written bf16 to Ab [b][s][h*64+d].
// ============================================================
__global__ __launch_bounds__(256) void k_attn(const unsigned short* __restrict__ Qh,
                                              const unsigned short* __restrict__ Kh,
                                              const unsigned short* __restrict__ Vt,
                                              unsigned short* __restrict__ Ab)
{
  __shared__ uint4 ldsu[2048];           // 32 KiB: Ks 8K | Vs 8K | Ps 16K
  char* Ks = (char*)ldsu;
  char* Vs = Ks + 8192;
  const int tid  = threadIdx.x;
  const int lane = tid & 63;
  const int w    = tid >> 6;
  char* Pw = Ks + 16384 + w*4096;

  const int qt = blockIdx.x, bh = blockIdx.y;
  const int q0 = qt * 128;
  const int qbase = q0 + w*32;
  const unsigned short* Qb = Qh + (size_t)bh*(SEQ*DK);
  const unsigned short* Kb = Kh + (size_t)bh*(SEQ*DK);
  const unsigned short* Vb = Vt + (size_t)bh*(SEQ*DK);
  const int b = bh >> 4, h = bh & 15;

  // Q fragments (A-operand): row = lane&15, k-chunk = (lane>>4)*8
  bf16x8 qf[2][2];
  #pragma unroll
  for (int qi = 0; qi < 2; ++qi)
    #pragma unroll
    for (int c = 0; c < 2; ++c)
      qf[qi][c] = *(const bf16x8*)(Qb + (size_t)(qbase + qi*16 + (lane & 15))*DK
                                      + c*32 + ((lane >> 4) << 3));

  f32x4 acc[2][4];
  f32x4 lsum[2], mrun[2];
  #pragma unroll
  for (int qi = 0; qi < 2; ++qi){
    #pragma unroll
    for (int df = 0; df < 4; ++df) acc[qi][df] = (f32x4)0.0f;
    lsum[qi] = (f32x4)0.0f;
    mrun[qi] = (f32x4)(-1e30f);
  }

  const int nkt = q0/64 + 2;
  const int wqmax = qbase + 31;

  for (int kt = 0; kt < nkt; ++kt){
    const int k0 = kt * 64;
    __syncthreads();                       // everyone done with prev tiles
    #pragma unroll
    for (int cc = 0; cc < 2; ++cc){        // stage K + Vt (8KB each)
      const int f = cc*256 + tid;
      const int r = f >> 3, slot = f & 7;
      const int sw = ((slot ^ (r & 7)) << 3);     // element offset of 16B chunk
      gload16(Kb + (size_t)(k0 + r)*DK + sw, Ks + (cc*256 + w*64)*16);
      gload16(Vb + (size_t)r*SEQ + k0 + sw, Vs + (cc*256 + w*64)*16);
    }
    __syncthreads();                       // stage complete (vmcnt drained)
    if (k0 > wqmax) continue;              // wave fully above diagonal

    // ---- S = Q K^T ----
    f32x4 sv[2][4];
    #pragma unroll
    for (int qi = 0; qi < 2; ++qi)
      #pragma unroll
      for (int kf = 0; kf < 4; ++kf) sv[qi][kf] = (f32x4)0.0f;
    #pragma unroll
    for (int kf = 0; kf < 4; ++kf){
      #pragma unroll
      for (int c = 0; c < 2; ++c){
        const int row = kf*16 + (lane & 15);
        const bf16x8 kfr = *(const bf16x8*)(Ks + row*128 +
            ((c*64 + ((lane >> 4) << 4)) ^ ((row & 7) << 4)));
        #pragma unroll
        for (int qi = 0; qi < 2; ++qi)
          sv[qi][kf] = __builtin_amdgcn_mfma_f32_16x16x32_bf16(qf[qi][c], kfr, sv[qi][kf], 0, 0, 0);
      }
    }

    // ---- causal mask (only near diagonal) ----
    if (k0 + 63 > qbase){
      #pragma unroll
      for (int qi = 0; qi < 2; ++qi)
        #pragma unroll
        for (int kf = 0; kf < 4; ++kf)
          #pragma unroll
          for (int r = 0; r < 4; ++r){
            const int q = qbase + qi*16 + ((lane >> 4) << 2) + r;
            const int k = k0 + kf*16 + (lane & 15);
            if (k > q) sv[qi][kf][r] = -1e30f;
          }
    }

    // ---- online softmax ----
    #pragma unroll
    for (int qi = 0; qi < 2; ++qi){
      f32x4 mx;
      #pragma unroll
      for (int r = 0; r < 4; ++r)
        mx[r] = fmaxf(fmaxf(sv[qi][0][r], sv[qi][1][r]),
                      fmaxf(sv[qi][2][r], sv[qi][3][r]));
      #pragma unroll
      for (int off = 1; off < 16; off <<= 1)
        #pragma unroll
        for (int r = 0; r < 4; ++r)
          mx[r] = fmaxf(mx[r], __shfl_xor(mx[r], off, 64));
      f32x4 mnew, corr;
      #pragma unroll
      for (int r = 0; r < 4; ++r){
        mnew[r] = fmaxf(mrun[qi][r], mx[r]);
        corr[r] = __expf(mrun[qi][r] - mnew[r]);
        mrun[qi][r] = mnew[r];
      }
      f32x4 psum = (f32x4)0.0f;
      #pragma unroll
      for (int kf = 0; kf < 4; ++kf)
        #pragma unroll
        for (int r = 0; r < 4; ++r){
          const float p = __expf(sv[qi][kf][r] - mnew[r]);
          sv[qi][kf][r] = p;
          psum[r] += p;
        }
      #pragma unroll
      for (int r = 0; r < 4; ++r)
        lsum[qi][r] = lsum[qi][r]*corr[r] + psum[r];
      #pragma unroll
      for (int df = 0; df < 4; ++df)
        #pragma unroll
        for (int r = 0; r < 4; ++r)
          acc[qi][df][r] *= corr[r];
      // P (C-layout) -> swizzled LDS, bf16
      #pragma unroll
      for (int kf = 0; kf < 4; ++kf)
        #pragma unroll
        for (int r = 0; r < 4; ++r){
          const int q  = qi*16 + ((lane >> 4) << 2) + r;
          const int kk = kf*16 + (lane & 15);
          *(unsigned short*)(Pw + q*128 + ((kk*2) ^ ((q & 7) << 4))) = f2bf(sv[qi][kf][r]);
        }
    }

    // ---- out += P V ----
    #pragma unroll
    for (int ks = 0; ks < 2; ++ks){
      bf16x8 pa[2];
      #pragma unroll
      for (int qi = 0; qi < 2; ++qi){
        const int row = qi*16 + (lane & 15);
        pa[qi] = *(const bf16x8*)(Pw + row*128 +
            ((ks*64 + ((lane >> 4) << 4)) ^ ((row & 7) << 4)));
      }
      #pragma unroll
      for (int df = 0; df < 4; ++df){
        const int row = df*16 + (lane & 15);
        const bf16x8 vf = *(const bf16x8*)(Vs + row*128 +
            ((ks*64 + ((lane >> 4) << 4)) ^ ((row & 7) << 4)));
        #pragma unroll
        for (int qi = 0; qi < 2; ++qi)
          acc[qi][df] = __builtin_amdgcn_mfma_f32_16x16x32_bf16(pa[qi], vf, acc[qi][df], 0, 0, 0);
      }
    }
  }

  // ---- final: reduce lsum across the 16-lane k-groups, normalize, store ----
  #pragma unroll
  for (int qi = 0; qi < 2; ++qi)
    #pragma unroll
    for (int off = 1; off < 16; off <<= 1)
      #pragma unroll
      for (int r = 0; r < 4; ++r)
        lsum[qi][r] += __shfl_xor(lsum[qi][r], off, 64);

  #pragma unroll
  for (int qi = 0; qi < 2; ++qi)
    #pragma unroll
    for (int r = 0; r < 4; ++r){
      const float inv = 1.0f / lsum[qi][r];
      const int srow = qbase + qi*16 + ((lane >> 4) << 2) + r;
      unsigned short* o = Ab + ((size_t)(b*SEQ + srow))*DM + h*DK;
      #pragma unroll
      for (int df = 0; df < 4; ++df)
        o[df*16 + (lane & 15)] = f2bf(acc[qi][df][r] * inv);
    }
}

// ============================================================
// launch
// ============================================================
extern "C" void kernel_launch(void* const* d_in, const int* in_sizes, int n_in,
                              void* d_out, int out_size, void* d_ws, size_t ws_size,
                              hipStream_t stream)
{
  (void)in_sizes; (void)n_in; (void)out_size;
  const float* x  = (const float*)d_in[0];
  const float* wq = (const float*)d_in[1];
  const float* wk = (const float*)d_in[2];
  const float* wv = (const float*)d_in[3];
  const float* wo = (const float*)d_in[4];
  const int* pos  = (const int*)d_in[5];
  float* out = (float*)d_out;

  // workspace layout (bytes); Ab (attn out) aliases xb (x no longer needed)
  if (ws_size < 92800000u) return;   // need ~88.5 MB
  char* ws = (char*)d_ws;
  unsigned short* xb = (unsigned short*)(ws);                 // 16 MB (also Ab)
  unsigned short* wb = (unsigned short*)(ws + 16777216);      //  8 MB (Wq|Wk|Wv|Wo)
  unsigned short* Qh = (unsigned short*)(ws + 25165824);      // 16 MB [b][h][s][d]
  unsigned short* Kh = (unsigned short*)(ws + 41943040);      // 16 MB
  unsigned short* Vh = (unsigned short*)(ws + 58720256);      // 16 MB
  unsigned short* Vt = (unsigned short*)(ws + 75497472);      // 16 MB [b][h][d][s]
  float* tab         = (float*)(ws + 92274688);               // 512 KB

  k_tables  <<<256, 256, 0, stream>>>(pos, tab);
  k_convert <<<12288, 256, 0, stream>>>(x, wq, wk, wv, wo, xb, wb);
  k_gemm<0> <<<dim3(64, 8, 3), 256, 0, stream>>>(xb, wb, wb + NW, wb + 2*NW,
                                                 Qh, Kh, Vh, nullptr);
  k_rope    <<<dim3(16384, 2), 256, 0, stream>>>(Qh, Kh, tab);
  k_transpose<<<dim3(32, 64), 256, 0, stream>>>(Vh, Vt);
  k_attn    <<<dim3(16, 64), 256, 0, stream>>>(Qh, Kh, Vt, xb);
  k_gemm<1> <<<dim3(64, 8, 1), 256, 0, stream>>>(xb, wb + 3*NW, nullptr, nullptr,
                                                 nullptr, nullptr, nullptr, out);
}

// Round 2
// 249.109 us; speedup vs baseline: 1.2767x; 1.2767x over previous
//
#include <hip/hip_runtime.h>
#include <stdint.h>

// ---------- types ----------
typedef __attribute__((ext_vector_type(8))) __bf16 bf16x8;
typedef __attribute__((ext_vector_type(4))) float f32x4;
typedef __attribute__((ext_vector_type(8))) unsigned short ushort8;

// ---------- helpers ----------
__device__ __forceinline__ float bf2f(unsigned short u){
  union { unsigned int i; float f; } v; v.i = ((unsigned int)u) << 16; return v.f;
}
__device__ __forceinline__ unsigned short f2bf(float f){
  union { float f; unsigned int i; } v; v.f = f;
  unsigned int r = v.i + 0x7fffu + ((v.i >> 16) & 1u);   // RNE
  return (unsigned short)(r >> 16);
}
__device__ __forceinline__ void gload16(const void* g, void* l){
  __builtin_amdgcn_global_load_lds((__attribute__((address_space(1))) void*)(g),
                                   (__attribute__((address_space(3))) void*)(l),
                                   16, 0, 0);
}

// ---------- constants ----------
#define SEQ   2048
#define DM    1024
#define NH    16
#define DK    64
#define BATCH 4
#define MTOT  (BATCH*SEQ)          // 8192
#define NX    (MTOT*DM)            // 8388608 elements in x
#define NW    (DM*DM)              // 1048576 per weight

// ============================================================
// sin/cos table: tab[s*32+i] = {cos, sin} of pos[s]*theta^(-2i/64)
// ============================================================
__global__ __launch_bounds__(256) void k_tables(const int* __restrict__ pos,
                                                float* __restrict__ tab)
{
  const int idx = blockIdx.x * 256 + threadIdx.x;    // 65536 total
  const int s = idx >> 5, i = idx & 31;
  const float inv = __expf(-0.28782313662425575f * (float)i);
  const float a = (float)pos[s] * inv;
  tab[2*idx]   = cosf(a);
  tab[2*idx+1] = sinf(a);
}

// ============================================================
// fp32 -> bf16 convert: x (8.4M) then Wq,Wk,Wv,Wo (1M each)
// ============================================================
__global__ __launch_bounds__(256) void k_convert(
    const float* __restrict__ x,  const float* __restrict__ wq,
    const float* __restrict__ wk, const float* __restrict__ wv,
    const float* __restrict__ wo,
    unsigned short* __restrict__ xb, unsigned short* __restrict__ wb)
{
  const long long tid = (long long)blockIdx.x * 256 + threadIdx.x;
  const long long e = tid * 4;
  const float* src; unsigned short* dst;
  if (e < NX) { src = x + e; dst = xb + e; }
  else {
    long long j = e - NX;
    int seg = (int)(j >> 20);            // /1048576
    long long off = j & 1048575;
    src = (seg==0?wq:seg==1?wk:seg==2?wv:wo) + off;
    dst = wb + (size_t)seg*NW + off;
  }
  float4 v = *(const float4*)src;
  unsigned long long pk =  (unsigned long long)f2bf(v.x)
                        | ((unsigned long long)f2bf(v.y) << 16)
                        | ((unsigned long long)f2bf(v.z) << 32)
                        | ((unsigned long long)f2bf(v.w) << 48);
  *(unsigned long long*)dst = pk;
}

// ============================================================
// NT GEMM: C[M=8192][N=1024] = A[M][K=1024] * W[N][K]^T  (bf16 MFMA)
// 128x128 tile, BK=32, 4 waves (2x2), m97-style global_load_lds staging.
// MODE 0: grid.z in {0,1,2} -> W{q,k,v}; z<2 write bf16 [b][h][s][d];
//         z==2 (V) writes bf16 TRANSPOSED [b][h][d][s] (kills k_transpose).
// MODE 1: write fp32 to Dout [M][N]
// ============================================================
#define BK 32
#define NTK (DM/BK)   // 32

template<int MODE>
__global__ __launch_bounds__(256) void k_gemm(
    const unsigned short* __restrict__ A,
    const unsigned short* __restrict__ W0,
    const unsigned short* __restrict__ W1,
    const unsigned short* __restrict__ W2,
    unsigned short* __restrict__ D0,
    unsigned short* __restrict__ D1,
    unsigned short* __restrict__ D2,
    float* __restrict__ Dout)
{
  __shared__ __attribute__((aligned(16))) unsigned short As[2][128*BK];
  __shared__ __attribute__((aligned(16))) unsigned short Bs[2][128*BK];
  const int tid  = threadIdx.x;
  const int lane = tid & 63;
  const int wv   = tid >> 6;
  const int wm = wv >> 1, wn = wv & 1;
  const int m0 = blockIdx.x * 128;
  const int n0 = blockIdx.y * 128;

  const unsigned short* W;
  unsigned short* Dh = nullptr;
  bool vtr = false;
  if (MODE == 0) {
    const int z = blockIdx.z;
    W  = (z == 0) ? W0 : (z == 1) ? W1 : W2;
    Dh = (z == 0) ? D0 : (z == 1) ? D1 : D2;
    vtr = (z == 2);
  } else {
    W = W0;
  }

  f32x4 acc[4][4];
  #pragma unroll
  for (int i = 0; i < 4; ++i)
    #pragma unroll
    for (int j = 0; j < 4; ++j)
      acc[i][j] = (f32x4)0.0f;

  auto stage = [&](int buf, int t){
    const int k0 = t * BK;
    #pragma unroll
    for (int cc = 0; cc < 2; ++cc){
      const int f = cc*256 + tid;
      const int row = f >> 2, kc = f & 3;
      gload16(A + (size_t)(m0 + row)*DM + k0 + kc*8,
              (char*)&As[buf][0] + (cc*256 + wv*64)*16);
      gload16(W + (size_t)(n0 + row)*DM + k0 + kc*8,
              (char*)&Bs[buf][0] + (cc*256 + wv*64)*16);
    }
  };

  stage(0, 0);
  __syncthreads();
  int cur = 0;
  for (int t = 0; t < NTK; ++t){
    if (t + 1 < NTK) stage(cur ^ 1, t + 1);
    const char* Ab_ = (const char*)&As[cur][0];
    const char* Bb_ = (const char*)&Bs[cur][0];
    bf16x8 af[4], bfr[4];
    #pragma unroll
    for (int i = 0; i < 4; ++i){
      af[i]  = *(const bf16x8*)(Ab_ + (wm*64 + i*16 + (lane & 15))*64 + ((lane >> 4) << 4));
      bfr[i] = *(const bf16x8*)(Bb_ + (wn*64 + i*16 + (lane & 15))*64 + ((lane >> 4) << 4));
    }
    #pragma unroll
    for (int i = 0; i < 4; ++i)
      #pragma unroll
      for (int j = 0; j < 4; ++j)
        acc[i][j] = __builtin_amdgcn_mfma_f32_16x16x32_bf16(af[i], bfr[j], acc[i][j], 0, 0, 0);
    __syncthreads();
    cur ^= 1;
  }

  // epilogue: C row = (lane>>4)*4+r, col = lane&15 (verified m89/m91 layout)
  #pragma unroll
  for (int i = 0; i < 4; ++i)
    #pragma unroll
    for (int j = 0; j < 4; ++j)
      #pragma unroll
      for (int r = 0; r < 4; ++r){
        const int m = m0 + wm*64 + i*16 + ((lane >> 4) << 2) + r;
        const int n = n0 + wn*64 + j*16 + (lane & 15);
        if (MODE == 0){
          const int b = m >> 11, s = m & 2047, hh = n >> 6, d = n & 63;
          if (vtr)
            Dh[(((size_t)(b*NH + hh))*DK + d)*SEQ + s] = f2bf(acc[i][j][r]);
          else
            Dh[((size_t)((b*NH + hh)*SEQ + s))*DK + d] = f2bf(acc[i][j][r]);
        } else {
          Dout[(size_t)m * DM + n] = acc[i][j][r];
        }
      }
}

// ============================================================
// RoPE in place on Qh/Kh [bh][s][64]; Q pre-scaled by 1/8.
// blockIdx.y: 0 -> Q, 1 -> K. One thread per (even,odd) pair.
// ============================================================
__global__ __launch_bounds__(256) void k_rope(unsigned short* __restrict__ Qh,
                                              unsigned short* __restrict__ Kh,
                                              const float* __restrict__ tab)
{
  const int idx = blockIdx.x * 256 + threadIdx.x;   // 4194304 per tensor
  const int z = blockIdx.y;
  const int s = (idx >> 5) & (SEQ-1);
  const int i = idx & 31;
  unsigned int* p = (unsigned int*)(z ? Kh : Qh) + idx;  // pair index == uint index
  const float scale = z ? 1.0f : 0.125f;
  const unsigned int v = *p;
  const float xe = bf2f((unsigned short)(v & 0xffff));
  const float xo = bf2f((unsigned short)(v >> 16));
  const float c  = tab[2*(s*32+i)];
  const float sn = tab[2*(s*32+i)+1];
  const float oe = (c*xe - sn*xo) * scale;
  const float oo = (sn*xe + c*xo) * scale;
  *p = (unsigned int)f2bf(oe) | ((unsigned int)f2bf(oo) << 16);
}

// ============================================================
// Causal flash attention, load-balanced + double-buffered.
// Block = 4 waves; each block processes q-tile (15-j) THEN q-tile j,
// so every block does exactly 34 k-tiles (perfect balance).
// K tile 64x64 and Vt tile 64x64 staged via global_load_lds with
// pre-swizzled SOURCE (XOR ((row&7)<<4)); tile kt+1 prefetched into the
// other LDS buffer while computing kt (end-of-iter __syncthreads drains
// vmcnt -> staged data visible next iter).
// ============================================================
__global__ __launch_bounds__(256) void k_attn(const unsigned short* __restrict__ Qh,
                                              const unsigned short* __restrict__ Kh,
                                              const unsigned short* __restrict__ Vt,
                                              unsigned short* __restrict__ Ab)
{
  __shared__ uint4 ldsu[3072];   // 48 KiB: [K0 8K|V0 8K][K1 8K|V1 8K][P 16K]
  char* base = (char*)ldsu;
  const int tid  = threadIdx.x;
  const int lane = tid & 63;
  const int w    = tid >> 6;
  char* Pw = base + 32768 + w*4096;

  const int jj = blockIdx.x, bh = blockIdx.y;
  const unsigned short* Qb = Qh + (size_t)bh*(SEQ*DK);
  const unsigned short* Kb = Kh + (size_t)bh*(SEQ*DK);
  const unsigned short* Vb = Vt + (size_t)bh*(SEQ*DK);
  const int b = bh >> 4, h = bh & 15;

  for (int pass = 0; pass < 2; ++pass){
    const int qt = pass ? jj : 15 - jj;
    const int q0 = qt * 128;
    const int qbase = q0 + w*32;

    // Q fragments (A-operand): row = lane&15, k-chunk = (lane>>4)*8
    bf16x8 qf[2][2];
    #pragma unroll
    for (int qi = 0; qi < 2; ++qi)
      #pragma unroll
      for (int c = 0; c < 2; ++c)
        qf[qi][c] = *(const bf16x8*)(Qb + (size_t)(qbase + qi*16 + (lane & 15))*DK
                                        + c*32 + ((lane >> 4) << 3));

    f32x4 acc[2][4];
    f32x4 lsum[2], mrun[2];
    #pragma unroll
    for (int qi = 0; qi < 2; ++qi){
      #pragma unroll
      for (int df = 0; df < 4; ++df) acc[qi][df] = (f32x4)0.0f;
      lsum[qi] = (f32x4)0.0f;
      mrun[qi] = (f32x4)(-1e30f);
    }

    const int nkt = 2*qt + 2;
    const int wqmax = qbase + 31;

    auto stage = [&](int buf, int kt){
      const int k0 = kt * 64;
      char* Kd = base + buf*16384;
      char* Vd = Kd + 8192;
      #pragma unroll
      for (int cc = 0; cc < 2; ++cc){
        const int f = cc*256 + tid;
        const int r = f >> 3, slot = f & 7;
        const int sw = ((slot ^ (r & 7)) << 3);     // element offset of 16B chunk
        gload16(Kb + (size_t)(k0 + r)*DK + sw, Kd + (cc*256 + w*64)*16);
        gload16(Vb + (size_t)r*SEQ + k0 + sw, Vd + (cc*256 + w*64)*16);
      }
    };

    if (pass) __syncthreads();     // safety: LDS reuse across passes
    stage(0, 0);
    __syncthreads();               // drains vmcnt -> tile 0 visible
    int cur = 0;

    for (int kt = 0; kt < nkt; ++kt){
      const int k0 = kt * 64;
      if (kt + 1 < nkt) stage(cur ^ 1, kt + 1);   // prefetch overlaps compute
      if (k0 <= wqmax){
        char* Ks = base + cur*16384;
        char* Vs = Ks + 8192;

        // ---- S = Q K^T ----
        f32x4 sv[2][4];
        #pragma unroll
        for (int qi = 0; qi < 2; ++qi)
          #pragma unroll
          for (int kf = 0; kf < 4; ++kf) sv[qi][kf] = (f32x4)0.0f;
        #pragma unroll
        for (int kf = 0; kf < 4; ++kf){
          #pragma unroll
          for (int c = 0; c < 2; ++c){
            const int row = kf*16 + (lane & 15);
            const bf16x8 kfr = *(const bf16x8*)(Ks + row*128 +
                ((c*64 + ((lane >> 4) << 4)) ^ ((row & 7) << 4)));
            #pragma unroll
            for (int qi = 0; qi < 2; ++qi)
              sv[qi][kf] = __builtin_amdgcn_mfma_f32_16x16x32_bf16(qf[qi][c], kfr, sv[qi][kf], 0, 0, 0);
          }
        }

        // ---- causal mask (only near diagonal) ----
        if (k0 + 63 > qbase){
          #pragma unroll
          for (int qi = 0; qi < 2; ++qi)
            #pragma unroll
            for (int kf = 0; kf < 4; ++kf)
              #pragma unroll
              for (int r = 0; r < 4; ++r){
                const int q = qbase + qi*16 + ((lane >> 4) << 2) + r;
                const int k = k0 + kf*16 + (lane & 15);
                if (k > q) sv[qi][kf][r] = -1e30f;
              }
        }

        // ---- online softmax ----
        #pragma unroll
        for (int qi = 0; qi < 2; ++qi){
          f32x4 mx;
          #pragma unroll
          for (int r = 0; r < 4; ++r)
            mx[r] = fmaxf(fmaxf(sv[qi][0][r], sv[qi][1][r]),
                          fmaxf(sv[qi][2][r], sv[qi][3][r]));
          #pragma unroll
          for (int off = 1; off < 16; off <<= 1)
            #pragma unroll
            for (int r = 0; r < 4; ++r)
              mx[r] = fmaxf(mx[r], __shfl_xor(mx[r], off, 64));
          f32x4 mnew, corr;
          #pragma unroll
          for (int r = 0; r < 4; ++r){
            mnew[r] = fmaxf(mrun[qi][r], mx[r]);
            corr[r] = __expf(mrun[qi][r] - mnew[r]);
            mrun[qi][r] = mnew[r];
          }
          f32x4 psum = (f32x4)0.0f;
          #pragma unroll
          for (int kf = 0; kf < 4; ++kf)
            #pragma unroll
            for (int r = 0; r < 4; ++r){
              const float p = __expf(sv[qi][kf][r] - mnew[r]);
              sv[qi][kf][r] = p;
              psum[r] += p;
            }
          #pragma unroll
          for (int r = 0; r < 4; ++r)
            lsum[qi][r] = lsum[qi][r]*corr[r] + psum[r];
          #pragma unroll
          for (int df = 0; df < 4; ++df)
            #pragma unroll
            for (int r = 0; r < 4; ++r)
              acc[qi][df][r] *= corr[r];
          // P (C-layout) -> swizzled LDS, bf16
          #pragma unroll
          for (int kf = 0; kf < 4; ++kf)
            #pragma unroll
            for (int r = 0; r < 4; ++r){
              const int q  = qi*16 + ((lane >> 4) << 2) + r;
              const int kk = kf*16 + (lane & 15);
              *(unsigned short*)(Pw + q*128 + ((kk*2) ^ ((q & 7) << 4))) = f2bf(sv[qi][kf][r]);
            }
        }

        // ---- out += P V ----
        #pragma unroll
        for (int ks = 0; ks < 2; ++ks){
          bf16x8 pa[2];
          #pragma unroll
          for (int qi = 0; qi < 2; ++qi){
            const int row = qi*16 + (lane & 15);
            pa[qi] = *(const bf16x8*)(Pw + row*128 +
                ((ks*64 + ((lane >> 4) << 4)) ^ ((row & 7) << 4)));
          }
          #pragma unroll
          for (int df = 0; df < 4; ++df){
            const int row = df*16 + (lane & 15);
            const bf16x8 vf = *(const bf16x8*)(Vs + row*128 +
                ((ks*64 + ((lane >> 4) << 4)) ^ ((row & 7) << 4)));
            #pragma unroll
            for (int qi = 0; qi < 2; ++qi)
              acc[qi][df] = __builtin_amdgcn_mfma_f32_16x16x32_bf16(pa[qi], vf, acc[qi][df], 0, 0, 0);
          }
        }
      }
      __syncthreads();             // compute done + prefetch vmcnt drained
      cur ^= 1;
    }

    // ---- final: reduce lsum across the 16-lane k-groups, normalize, store ----
    #pragma unroll
    for (int qi = 0; qi < 2; ++qi)
      #pragma unroll
      for (int off = 1; off < 16; off <<= 1)
        #pragma unroll
        for (int r = 0; r < 4; ++r)
          lsum[qi][r] += __shfl_xor(lsum[qi][r], off, 64);

    #pragma unroll
    for (int qi = 0; qi < 2; ++qi)
      #pragma unroll
      for (int r = 0; r < 4; ++r){
        const float inv = 1.0f / lsum[qi][r];
        const int srow = qbase + qi*16 + ((lane >> 4) << 2) + r;
        unsigned short* o = Ab + ((size_t)(b*SEQ + srow))*DM + h*DK;
        #pragma unroll
        for (int df = 0; df < 4; ++df)
          o[df*16 + (lane & 15)] = f2bf(acc[qi][df][r] * inv);
      }
  }
}

// ============================================================
// launch
// ============================================================
extern "C" void kernel_launch(void* const* d_in, const int* in_sizes, int n_in,
                              void* d_out, int out_size, void* d_ws, size_t ws_size,
                              hipStream_t stream)
{
  (void)in_sizes; (void)n_in; (void)out_size;
  const float* x  = (const float*)d_in[0];
  const float* wq = (const float*)d_in[1];
  const float* wk = (const float*)d_in[2];
  const float* wv = (const float*)d_in[3];
  const float* wo = (const float*)d_in[4];
  const int* pos  = (const int*)d_in[5];
  float* out = (float*)d_out;

  // workspace layout (bytes); Ab (attn out) aliases xb (x no longer needed)
  if (ws_size < 92800000u) return;   // need ~88.5 MB
  char* ws = (char*)d_ws;
  unsigned short* xb = (unsigned short*)(ws);                 // 16 MB (also Ab)
  unsigned short* wb = (unsigned short*)(ws + 16777216);      //  8 MB (Wq|Wk|Wv|Wo)
  unsigned short* Qh = (unsigned short*)(ws + 25165824);      // 16 MB [b][h][s][d]
  unsigned short* Kh = (unsigned short*)(ws + 41943040);      // 16 MB
  unsigned short* Vt = (unsigned short*)(ws + 75497472);      // 16 MB [b][h][d][s]
  float* tab         = (float*)(ws + 92274688);               // 512 KB

  k_tables  <<<256, 256, 0, stream>>>(pos, tab);
  k_convert <<<12288, 256, 0, stream>>>(x, wq, wk, wv, wo, xb, wb);
  k_gemm<0> <<<dim3(64, 8, 3), 256, 0, stream>>>(xb, wb, wb + NW, wb + 2*NW,
                                                 Qh, Kh, Vt, nullptr);
  k_rope    <<<dim3(16384, 2), 256, 0, stream>>>(Qh, Kh, tab);
  k_attn    <<<dim3(8, 64), 256, 0, stream>>>(Qh, Kh, Vt, xb);
  k_gemm<1> <<<dim3(64, 8, 1), 256, 0, stream>>>(xb, wb + 3*NW, nullptr, nullptr,
                                                 nullptr, nullptr, nullptr, out);
}

// Round 4
// 247.018 us; speedup vs baseline: 1.2875x; 1.0085x over previous
//
#include <hip/hip_runtime.h>
#include <stdint.h>

// ---------- types ----------
typedef __attribute__((ext_vector_type(8))) __bf16 bf16x8;
typedef __attribute__((ext_vector_type(4))) float f32x4;
typedef __attribute__((ext_vector_type(8))) unsigned short ushort8;

// ---------- helpers ----------
__device__ __forceinline__ unsigned short f2bf(float f){
  union { float f; unsigned int i; } v; v.f = f;
  unsigned int r = v.i + 0x7fffu + ((v.i >> 16) & 1u);   // RNE
  return (unsigned short)(r >> 16);
}
__device__ __forceinline__ void gload16(const void* g, void* l){
  __builtin_amdgcn_global_load_lds((__attribute__((address_space(1))) void*)(g),
                                   (__attribute__((address_space(3))) void*)(l),
                                   16, 0, 0);
}

// ---------- constants ----------
#define SEQ   2048
#define DM    1024
#define NH    16
#define DK    64
#define BATCH 4
#define MTOT  (BATCH*SEQ)          // 8192
#define NX    (MTOT*DM)            // 8388608 elements in x
#define NW    (DM*DM)              // 1048576 per weight

#define QSCALE 0.18033688011112f   // (1/8) * log2(e)  -> softmax in exp2 domain
#define DEFER_THR 11.5f            // log2-domain rescale threshold (~HK THR=8 ln)

// ============================================================
// sin/cos table: tab[s*32+i] = {cos, sin} of pos[s]*theta^(-2i/64)
// ============================================================
__global__ __launch_bounds__(256) void k_tables(const int* __restrict__ pos,
                                                float* __restrict__ tab)
{
  const int idx = blockIdx.x * 256 + threadIdx.x;    // 65536 total
  const int s = idx >> 5, i = idx & 31;
  const float inv = __expf(-0.28782313662425575f * (float)i);
  const float a = (float)pos[s] * inv;
  tab[2*idx]   = cosf(a);
  tab[2*idx+1] = sinf(a);
}

// ============================================================
// fp32 -> bf16 convert: x (8.4M) then Wq,Wk,Wv,Wo (1M each)
// ============================================================
__global__ __launch_bounds__(256) void k_convert(
    const float* __restrict__ x,  const float* __restrict__ wq,
    const float* __restrict__ wk, const float* __restrict__ wv,
    const float* __restrict__ wo,
    unsigned short* __restrict__ xb, unsigned short* __restrict__ wb)
{
  const long long tid = (long long)blockIdx.x * 256 + threadIdx.x;
  const long long e = tid * 4;
  const float* src; unsigned short* dst;
  if (e < NX) { src = x + e; dst = xb + e; }
  else {
    long long j = e - NX;
    int seg = (int)(j >> 20);            // /1048576
    long long off = j & 1048575;
    src = (seg==0?wq:seg==1?wk:seg==2?wv:wo) + off;
    dst = wb + (size_t)seg*NW + off;
  }
  float4 v = *(const float4*)src;
  unsigned long long pk =  (unsigned long long)f2bf(v.x)
                        | ((unsigned long long)f2bf(v.y) << 16)
                        | ((unsigned long long)f2bf(v.z) << 32)
                        | ((unsigned long long)f2bf(v.w) << 48);
  *(unsigned long long*)dst = pk;
}

// ============================================================
// NT GEMM: C[M=8192][N=1024] = A[M][K=1024] * W[N][K]^T  (bf16 MFMA)
// 128x128 tile, BK=32, 4 waves (2x2), m97-style global_load_lds staging.
// MODE 0: z in {0,1,2} -> W{q,k,v}; z<2 apply RoPE in epilogue (Q also
//         scaled by QSCALE) and write bf16 [b][h][s][d]; z==2 (V) writes
//         bf16 TRANSPOSED [b][h][d][s].
// MODE 1: write fp32 to Dout [M][N]
// ============================================================
#define BK 32
#define NTK (DM/BK)   // 32

template<int MODE>
__global__ __launch_bounds__(256) void k_gemm(
    const unsigned short* __restrict__ A,
    const unsigned short* __restrict__ W0,
    const unsigned short* __restrict__ W1,
    const unsigned short* __restrict__ W2,
    unsigned short* __restrict__ D0,
    unsigned short* __restrict__ D1,
    unsigned short* __restrict__ D2,
    float* __restrict__ Dout,
    const float* __restrict__ tab)
{
  __shared__ __attribute__((aligned(16))) unsigned short As[2][128*BK];
  __shared__ __attribute__((aligned(16))) unsigned short Bs[2][128*BK];
  const int tid  = threadIdx.x;
  const int lane = tid & 63;
  const int wv   = tid >> 6;
  const int wm = wv >> 1, wn = wv & 1;
  const int m0 = blockIdx.x * 128;
  const int n0 = blockIdx.y * 128;

  const unsigned short* W;
  unsigned short* Dh = nullptr;
  bool vtr = false;
  if (MODE == 0) {
    const int z = blockIdx.z;
    W  = (z == 0) ? W0 : (z == 1) ? W1 : W2;
    Dh = (z == 0) ? D0 : (z == 1) ? D1 : D2;
    vtr = (z == 2);
  } else {
    W = W0;
  }

  f32x4 acc[4][4];
  #pragma unroll
  for (int i = 0; i < 4; ++i)
    #pragma unroll
    for (int j = 0; j < 4; ++j)
      acc[i][j] = (f32x4)0.0f;

  auto stage = [&](int buf, int t){
    const int k0 = t * BK;
    #pragma unroll
    for (int cc = 0; cc < 2; ++cc){
      const int f = cc*256 + tid;
      const int row = f >> 2, kc = f & 3;
      gload16(A + (size_t)(m0 + row)*DM + k0 + kc*8,
              (char*)&As[buf][0] + (cc*256 + wv*64)*16);
      gload16(W + (size_t)(n0 + row)*DM + k0 + kc*8,
              (char*)&Bs[buf][0] + (cc*256 + wv*64)*16);
    }
  };

  stage(0, 0);
  __syncthreads();
  int cur = 0;
  for (int t = 0; t < NTK; ++t){
    if (t + 1 < NTK) stage(cur ^ 1, t + 1);
    const char* Ab_ = (const char*)&As[cur][0];
    const char* Bb_ = (const char*)&Bs[cur][0];
    bf16x8 af[4], bfr[4];
    #pragma unroll
    for (int i = 0; i < 4; ++i){
      af[i]  = *(const bf16x8*)(Ab_ + (wm*64 + i*16 + (lane & 15))*64 + ((lane >> 4) << 4));
      bfr[i] = *(const bf16x8*)(Bb_ + (wn*64 + i*16 + (lane & 15))*64 + ((lane >> 4) << 4));
    }
    __builtin_amdgcn_s_setprio(1);
    #pragma unroll
    for (int i = 0; i < 4; ++i)
      #pragma unroll
      for (int j = 0; j < 4; ++j)
        acc[i][j] = __builtin_amdgcn_mfma_f32_16x16x32_bf16(af[i], bfr[j], acc[i][j], 0, 0, 0);
    __builtin_amdgcn_s_setprio(0);
    __syncthreads();
    cur ^= 1;
  }

  // epilogue: C row = (lane>>4)*4+r, col = lane&15 (verified m89/m91 layout)
  if (MODE == 0 && !vtr){
    // fused RoPE: pairs (2i,2i+1) of d live in adjacent lanes -> shfl_xor(1)
    const float scale = (blockIdx.z == 0) ? QSCALE : 1.0f;
    #pragma unroll
    for (int i = 0; i < 4; ++i)
      #pragma unroll
      for (int j = 0; j < 4; ++j)
        #pragma unroll
        for (int r = 0; r < 4; ++r){
          const int m = m0 + wm*64 + i*16 + ((lane >> 4) << 2) + r;
          const int n = n0 + wn*64 + j*16 + (lane & 15);
          const float v  = acc[i][j][r];
          const float vp = __shfl_xor(v, 1, 64);
          const int sp = m & 2047, d = n & 63;
          const float2 cs = ((const float2*)tab)[sp*32 + (d >> 1)];
          const float o = ((n & 1) ? (cs.y*vp + cs.x*v) : (cs.x*v - cs.y*vp)) * scale;
          const int b = m >> 11, hh = n >> 6;
          *(__bf16*)&Dh[((size_t)((b*NH + hh)*SEQ + sp))*DK + d] = (__bf16)o;
        }
  } else {
    #pragma unroll
    for (int i = 0; i < 4; ++i)
      #pragma unroll
      for (int j = 0; j < 4; ++j)
        #pragma unroll
        for (int r = 0; r < 4; ++r){
          const int m = m0 + wm*64 + i*16 + ((lane >> 4) << 2) + r;
          const int n = n0 + wn*64 + j*16 + (lane & 15);
          if (MODE == 0){
            const int b = m >> 11, sp = m & 2047, hh = n >> 6, d = n & 63;
            *(__bf16*)&Dh[(((size_t)(b*NH + hh))*DK + d)*SEQ + sp] = (__bf16)acc[i][j][r];
          } else {
            Dout[(size_t)m * DM + n] = acc[i][j][r];
          }
        }
  }
}

// ============================================================
// Causal flash attention, load-balanced + double-buffered.
// Block = 4 waves; each block processes q-tile (15-j) THEN q-tile j,
// so every block does exactly 34 k-tiles (perfect balance).
// Softmax in exp2 domain (Q pre-scaled by log2e/8) with defer-rescale.
// K/Vt tiles staged via global_load_lds with pre-swizzled SOURCE
// (XOR ((row&7)<<4)); tile kt+1 prefetched during compute of kt.
// ============================================================
__global__ __launch_bounds__(256) void k_attn(const unsigned short* __restrict__ Qh,
                                              const unsigned short* __restrict__ Kh,
                                              const unsigned short* __restrict__ Vt,
                                              unsigned short* __restrict__ Ab)
{
  __shared__ uint4 ldsu[3072];   // 48 KiB: [K0 8K|V0 8K][K1 8K|V1 8K][P 16K]
  char* base = (char*)ldsu;
  const int tid  = threadIdx.x;
  const int lane = tid & 63;
  const int w    = tid >> 6;
  char* Pw = base + 32768 + w*4096;

  const int jj = blockIdx.x, bh = blockIdx.y;
  const unsigned short* Qb = Qh + (size_t)bh*(SEQ*DK);
  const unsigned short* Kb = Kh + (size_t)bh*(SEQ*DK);
  const unsigned short* Vb = Vt + (size_t)bh*(SEQ*DK);
  const int b = bh >> 4, h = bh & 15;

  for (int pass = 0; pass < 2; ++pass){
    const int qt = pass ? jj : 15 - jj;
    const int q0 = qt * 128;
    const int qbase = q0 + w*32;

    // Q fragments (A-operand): row = lane&15, k-chunk = (lane>>4)*8
    bf16x8 qf[2][2];
    #pragma unroll
    for (int qi = 0; qi < 2; ++qi)
      #pragma unroll
      for (int c = 0; c < 2; ++c)
        qf[qi][c] = *(const bf16x8*)(Qb + (size_t)(qbase + qi*16 + (lane & 15))*DK
                                        + c*32 + ((lane >> 4) << 3));

    f32x4 acc[2][4];
    f32x4 lsum[2], mrun[2];
    #pragma unroll
    for (int qi = 0; qi < 2; ++qi){
      #pragma unroll
      for (int df = 0; df < 4; ++df) acc[qi][df] = (f32x4)0.0f;
      lsum[qi] = (f32x4)0.0f;
      mrun[qi] = (f32x4)(-1e30f);
    }

    const int nkt = 2*qt + 2;
    const int wqmax = qbase + 31;

    auto stage = [&](int buf, int kt){
      const int k0 = kt * 64;
      char* Kd = base + buf*16384;
      char* Vd = Kd + 8192;
      #pragma unroll
      for (int cc = 0; cc < 2; ++cc){
        const int f = cc*256 + tid;
        const int r = f >> 3, slot = f & 7;
        const int sw = ((slot ^ (r & 7)) << 3);     // element offset of 16B chunk
        gload16(Kb + (size_t)(k0 + r)*DK + sw, Kd + (cc*256 + w*64)*16);
        gload16(Vb + (size_t)r*SEQ + k0 + sw, Vd + (cc*256 + w*64)*16);
      }
    };

    if (pass) __syncthreads();     // safety: LDS reuse across passes
    stage(0, 0);
    __syncthreads();               // drains vmcnt -> tile 0 visible
    int cur = 0;

    for (int kt = 0; kt < nkt; ++kt){
      const int k0 = kt * 64;
      if (kt + 1 < nkt) stage(cur ^ 1, kt + 1);   // prefetch overlaps compute
      if (k0 <= wqmax){
        char* Ks = base + cur*16384;
        char* Vs = Ks + 8192;

        // ---- S = Q K^T (exp2 domain) ----
        f32x4 sv[2][4];
        #pragma unroll
        for (int qi = 0; qi < 2; ++qi)
          #pragma unroll
          for (int kf = 0; kf < 4; ++kf) sv[qi][kf] = (f32x4)0.0f;
        __builtin_amdgcn_s_setprio(1);
        #pragma unroll
        for (int kf = 0; kf < 4; ++kf){
          #pragma unroll
          for (int c = 0; c < 2; ++c){
            const int row = kf*16 + (lane & 15);
            const bf16x8 kfr = *(const bf16x8*)(Ks + row*128 +
                ((c*64 + ((lane >> 4) << 4)) ^ ((row & 7) << 4)));
            #pragma unroll
            for (int qi = 0; qi < 2; ++qi)
              sv[qi][kf] = __builtin_amdgcn_mfma_f32_16x16x32_bf16(qf[qi][c], kfr, sv[qi][kf], 0, 0, 0);
          }
        }
        __builtin_amdgcn_s_setprio(0);

        // ---- causal mask (only the diagonal tile) ----
        if (k0 + 63 > qbase){
          #pragma unroll
          for (int qi = 0; qi < 2; ++qi)
            #pragma unroll
            for (int kf = 0; kf < 4; ++kf)
              #pragma unroll
              for (int r = 0; r < 4; ++r){
                const int q = qbase + qi*16 + ((lane >> 4) << 2) + r;
                const int k = k0 + kf*16 + (lane & 15);
                if (k > q) sv[qi][kf][r] = -1e30f;
              }
        }

        // ---- online softmax (exp2 domain, defer-rescale T13) ----
        f32x4 mx[2];
        float growth = -1e30f;
        #pragma unroll
        for (int qi = 0; qi < 2; ++qi){
          #pragma unroll
          for (int r = 0; r < 4; ++r)
            mx[qi][r] = fmaxf(fmaxf(sv[qi][0][r], sv[qi][1][r]),
                              fmaxf(sv[qi][2][r], sv[qi][3][r]));
          #pragma unroll
          for (int off = 1; off < 16; off <<= 1)
            #pragma unroll
            for (int r = 0; r < 4; ++r)
              mx[qi][r] = fmaxf(mx[qi][r], __shfl_xor(mx[qi][r], off, 64));
          #pragma unroll
          for (int r = 0; r < 4; ++r)
            growth = fmaxf(growth, mx[qi][r] - mrun[qi][r]);
        }
        if (!__all(growth <= DEFER_THR)){
          #pragma unroll
          for (int qi = 0; qi < 2; ++qi){
            f32x4 corr;
            #pragma unroll
            for (int r = 0; r < 4; ++r){
              const float mnew = fmaxf(mrun[qi][r], mx[qi][r]);
              corr[r] = exp2f(mrun[qi][r] - mnew);
              mrun[qi][r] = mnew;
              lsum[qi][r] *= corr[r];
            }
            #pragma unroll
            for (int df = 0; df < 4; ++df)
              #pragma unroll
              for (int r = 0; r < 4; ++r)
                acc[qi][df][r] *= corr[r];
          }
        }
        #pragma unroll
        for (int qi = 0; qi < 2; ++qi){
          f32x4 psum = (f32x4)0.0f;
          #pragma unroll
          for (int kf = 0; kf < 4; ++kf)
            #pragma unroll
            for (int r = 0; r < 4; ++r){
              const float p = exp2f(sv[qi][kf][r] - mrun[qi][r]);
              sv[qi][kf][r] = p;
              psum[r] += p;
            }
          #pragma unroll
          for (int r = 0; r < 4; ++r) lsum[qi][r] += psum[r];
          // P (C-layout) -> swizzled LDS, bf16
          #pragma unroll
          for (int kf = 0; kf < 4; ++kf)
            #pragma unroll
            for (int r = 0; r < 4; ++r){
              const int q  = qi*16 + ((lane >> 4) << 2) + r;
              const int kk = kf*16 + (lane & 15);
              *(__bf16*)(Pw + q*128 + ((kk*2) ^ ((q & 7) << 4))) = (__bf16)sv[qi][kf][r];
            }
        }

        // ---- out += P V ----
        #pragma unroll
        for (int ks = 0; ks < 2; ++ks){
          bf16x8 pa[2];
          #pragma unroll
          for (int qi = 0; qi < 2; ++qi){
            const int row = qi*16 + (lane & 15);
            pa[qi] = *(const bf16x8*)(Pw + row*128 +
                ((ks*64 + ((lane >> 4) << 4)) ^ ((row & 7) << 4)));
          }
          __builtin_amdgcn_s_setprio(1);
          #pragma unroll
          for (int df = 0; df < 4; ++df){
            const int row = df*16 + (lane & 15);
            const bf16x8 vf = *(const bf16x8*)(Vs + row*128 +
                ((ks*64 + ((lane >> 4) << 4)) ^ ((row & 7) << 4)));
            #pragma unroll
            for (int qi = 0; qi < 2; ++qi)
              acc[qi][df] = __builtin_amdgcn_mfma_f32_16x16x32_bf16(pa[qi], vf, acc[qi][df], 0, 0, 0);
          }
          __builtin_amdgcn_s_setprio(0);
        }
      }
      __syncthreads();             // compute done + prefetch vmcnt drained
      cur ^= 1;
    }

    // ---- final: reduce lsum across the 16-lane k-groups, normalize, store ----
    #pragma unroll
    for (int qi = 0; qi < 2; ++qi)
      #pragma unroll
      for (int off = 1; off < 16; off <<= 1)
        #pragma unroll
        for (int r = 0; r < 4; ++r)
          lsum[qi][r] += __shfl_xor(lsum[qi][r], off, 64);

    #pragma unroll
    for (int qi = 0; qi < 2; ++qi)
      #pragma unroll
      for (int r = 0; r < 4; ++r){
        const float inv = 1.0f / lsum[qi][r];
        const int srow = qbase + qi*16 + ((lane >> 4) << 2) + r;
        unsigned short* o = Ab + ((size_t)(b*SEQ + srow))*DM + h*DK;
        #pragma unroll
        for (int df = 0; df < 4; ++df)
          *(__bf16*)&o[df*16 + (lane & 15)] = (__bf16)(acc[qi][df][r] * inv);
      }
  }
}

// ============================================================
// launch
// ============================================================
extern "C" void kernel_launch(void* const* d_in, const int* in_sizes, int n_in,
                              void* d_out, int out_size, void* d_ws, size_t ws_size,
                              hipStream_t stream)
{
  (void)in_sizes; (void)n_in; (void)out_size;
  const float* x  = (const float*)d_in[0];
  const float* wq = (const float*)d_in[1];
  const float* wk = (const float*)d_in[2];
  const float* wv = (const float*)d_in[3];
  const float* wo = (const float*)d_in[4];
  const int* pos  = (const int*)d_in[5];
  float* out = (float*)d_out;

  // workspace layout (bytes); Ab (attn out) aliases xb (x no longer needed)
  if (ws_size < 92800000u) return;   // need ~88.5 MB
  char* ws = (char*)d_ws;
  unsigned short* xb = (unsigned short*)(ws);                 // 16 MB (also Ab)
  unsigned short* wb = (unsigned short*)(ws + 16777216);      //  8 MB (Wq|Wk|Wv|Wo)
  unsigned short* Qh = (unsigned short*)(ws + 25165824);      // 16 MB [b][h][s][d]
  unsigned short* Kh = (unsigned short*)(ws + 41943040);      // 16 MB
  unsigned short* Vt = (unsigned short*)(ws + 75497472);      // 16 MB [b][h][d][s]
  float* tab         = (float*)(ws + 92274688);               // 512 KB

  k_tables  <<<256, 256, 0, stream>>>(pos, tab);
  k_convert <<<12288, 256, 0, stream>>>(x, wq, wk, wv, wo, xb, wb);
  k_gemm<0> <<<dim3(64, 8, 3), 256, 0, stream>>>(xb, wb, wb + NW, wb + 2*NW,
                                                 Qh, Kh, Vt, nullptr, tab);
  k_attn    <<<dim3(8, 64), 256, 0, stream>>>(Qh, Kh, Vt, xb);
  k_gemm<1> <<<dim3(64, 8, 1), 256, 0, stream>>>(xb, wb + 3*NW, nullptr, nullptr,
                                                 nullptr, nullptr, nullptr, out, nullptr);
}

// Round 5
// 224.906 us; speedup vs baseline: 1.4141x; 1.0983x over previous
//
#include <hip/hip_runtime.h>
#include <stdint.h>

// ---------- types ----------
typedef __attribute__((ext_vector_type(8))) __bf16 bf16x8;
typedef __attribute__((ext_vector_type(4))) float f32x4;
typedef __attribute__((ext_vector_type(16))) float f32x16;
typedef __attribute__((ext_vector_type(8))) unsigned short ushort8;

// ---------- helpers ----------
__device__ __forceinline__ unsigned short f2bf(float f){
  union { float f; unsigned int i; } v; v.f = f;
  unsigned int r = v.i + 0x7fffu + ((v.i >> 16) & 1u);   // RNE
  return (unsigned short)(r >> 16);
}
__device__ __forceinline__ void gload16(const void* g, void* l){
  __builtin_amdgcn_global_load_lds((__attribute__((address_space(1))) void*)(g),
                                   (__attribute__((address_space(3))) void*)(l),
                                   16, 0, 0);
}
__device__ __forceinline__ unsigned int cvtpk(float lo, float hi){
  unsigned int r;
  asm("v_cvt_pk_bf16_f32 %0, %1, %2" : "=v"(r) : "v"(lo), "v"(hi));
  return r;
}
// swizzled LDS read of a 16B chunk from a [64][64] bf16 tile (128B rows)
__device__ __forceinline__ bf16x8 ldsw(const char* tile, int row, int colb){
  return *(const bf16x8*)(tile + row*128 + (colb ^ ((row & 7) << 4)));
}

// ---------- constants ----------
#define SEQ   2048
#define DM    1024
#define NH    16
#define DK    64
#define BATCH 4
#define MTOT  (BATCH*SEQ)          // 8192
#define NX    (MTOT*DM)            // 8388608 elements in x
#define NW    (DM*DM)              // 1048576 per weight

#define QSCALE 0.18033688011112f   // (1/8) * log2(e)  -> softmax in exp2 domain
#define DEFER_THR 11.5f            // log2-domain rescale threshold

// ============================================================
// sin/cos table: tab[s*32+i] = {cos, sin} of pos[s]*theta^(-2i/64)
// ============================================================
__global__ __launch_bounds__(256) void k_tables(const int* __restrict__ pos,
                                                float* __restrict__ tab)
{
  const int idx = blockIdx.x * 256 + threadIdx.x;    // 65536 total
  const int s = idx >> 5, i = idx & 31;
  const float inv = __expf(-0.28782313662425575f * (float)i);
  const float a = (float)pos[s] * inv;
  tab[2*idx]   = cosf(a);
  tab[2*idx+1] = sinf(a);
}

// ============================================================
// fp32 -> bf16 convert: x (8.4M) then Wq,Wk,Wv,Wo (1M each)
// ============================================================
__global__ __launch_bounds__(256) void k_convert(
    const float* __restrict__ x,  const float* __restrict__ wq,
    const float* __restrict__ wk, const float* __restrict__ wv,
    const float* __restrict__ wo,
    unsigned short* __restrict__ xb, unsigned short* __restrict__ wb)
{
  const long long tid = (long long)blockIdx.x * 256 + threadIdx.x;
  const long long e = tid * 4;
  const float* src; unsigned short* dst;
  if (e < NX) { src = x + e; dst = xb + e; }
  else {
    long long j = e - NX;
    int seg = (int)(j >> 20);            // /1048576
    long long off = j & 1048575;
    src = (seg==0?wq:seg==1?wk:seg==2?wv:wo) + off;
    dst = wb + (size_t)seg*NW + off;
  }
  float4 v = *(const float4*)src;
  unsigned long long pk =  (unsigned long long)f2bf(v.x)
                        | ((unsigned long long)f2bf(v.y) << 16)
                        | ((unsigned long long)f2bf(v.z) << 32)
                        | ((unsigned long long)f2bf(v.w) << 48);
  *(unsigned long long*)dst = pk;
}

// ============================================================
// NT GEMM: C[M=8192][N=1024] = A[M][K=1024] * W[N][K]^T  (bf16 MFMA)
// 128x128 tile, BK=32, 4 waves (2x2), m97-style global_load_lds staging.
// MODE 0: z in {0,1,2} -> W{q,k,v}; z<2 apply RoPE in epilogue (Q also
//         scaled by QSCALE) and write bf16 [b][h][s][d]; z==2 (V) writes
//         bf16 TRANSPOSED [b][h][d][s].
// MODE 1: write fp32 to Dout [M][N]
// ============================================================
#define BK 32
#define NTK (DM/BK)   // 32

template<int MODE>
__global__ __launch_bounds__(256) void k_gemm(
    const unsigned short* __restrict__ A,
    const unsigned short* __restrict__ W0,
    const unsigned short* __restrict__ W1,
    const unsigned short* __restrict__ W2,
    unsigned short* __restrict__ D0,
    unsigned short* __restrict__ D1,
    unsigned short* __restrict__ D2,
    float* __restrict__ Dout,
    const float* __restrict__ tab)
{
  __shared__ __attribute__((aligned(16))) unsigned short As[2][128*BK];
  __shared__ __attribute__((aligned(16))) unsigned short Bs[2][128*BK];
  const int tid  = threadIdx.x;
  const int lane = tid & 63;
  const int wv   = tid >> 6;
  const int wm = wv >> 1, wn = wv & 1;
  const int m0 = blockIdx.x * 128;
  const int n0 = blockIdx.y * 128;

  const unsigned short* W;
  unsigned short* Dh = nullptr;
  bool vtr = false;
  if (MODE == 0) {
    const int z = blockIdx.z;
    W  = (z == 0) ? W0 : (z == 1) ? W1 : W2;
    Dh = (z == 0) ? D0 : (z == 1) ? D1 : D2;
    vtr = (z == 2);
  } else {
    W = W0;
  }

  f32x4 acc[4][4];
  #pragma unroll
  for (int i = 0; i < 4; ++i)
    #pragma unroll
    for (int j = 0; j < 4; ++j)
      acc[i][j] = (f32x4)0.0f;

  auto stage = [&](int buf, int t){
    const int k0 = t * BK;
    #pragma unroll
    for (int cc = 0; cc < 2; ++cc){
      const int f = cc*256 + tid;
      const int row = f >> 2, kc = f & 3;
      gload16(A + (size_t)(m0 + row)*DM + k0 + kc*8,
              (char*)&As[buf][0] + (cc*256 + wv*64)*16);
      gload16(W + (size_t)(n0 + row)*DM + k0 + kc*8,
              (char*)&Bs[buf][0] + (cc*256 + wv*64)*16);
    }
  };

  stage(0, 0);
  __syncthreads();
  int cur = 0;
  for (int t = 0; t < NTK; ++t){
    if (t + 1 < NTK) stage(cur ^ 1, t + 1);
    const char* Ab_ = (const char*)&As[cur][0];
    const char* Bb_ = (const char*)&Bs[cur][0];
    bf16x8 af[4], bfr[4];
    #pragma unroll
    for (int i = 0; i < 4; ++i){
      af[i]  = *(const bf16x8*)(Ab_ + (wm*64 + i*16 + (lane & 15))*64 + ((lane >> 4) << 4));
      bfr[i] = *(const bf16x8*)(Bb_ + (wn*64 + i*16 + (lane & 15))*64 + ((lane >> 4) << 4));
    }
    #pragma unroll
    for (int i = 0; i < 4; ++i)
      #pragma unroll
      for (int j = 0; j < 4; ++j)
        acc[i][j] = __builtin_amdgcn_mfma_f32_16x16x32_bf16(af[i], bfr[j], acc[i][j], 0, 0, 0);
    __syncthreads();
    cur ^= 1;
  }

  // epilogue: C row = (lane>>4)*4+r, col = lane&15 (verified m89/m91 layout)
  if (MODE == 0 && !vtr){
    // fused RoPE: pairs (2i,2i+1) of d live in adjacent lanes -> shfl_xor(1)
    const float scale = (blockIdx.z == 0) ? QSCALE : 1.0f;
    #pragma unroll
    for (int i = 0; i < 4; ++i)
      #pragma unroll
      for (int j = 0; j < 4; ++j)
        #pragma unroll
        for (int r = 0; r < 4; ++r){
          const int m = m0 + wm*64 + i*16 + ((lane >> 4) << 2) + r;
          const int n = n0 + wn*64 + j*16 + (lane & 15);
          const float v  = acc[i][j][r];
          const float vp = __shfl_xor(v, 1, 64);
          const int sp = m & 2047, d = n & 63;
          const float2 cs = ((const float2*)tab)[sp*32 + (d >> 1)];
          const float o = ((n & 1) ? (cs.y*vp + cs.x*v) : (cs.x*v - cs.y*vp)) * scale;
          const int b = m >> 11, hh = n >> 6;
          *(__bf16*)&Dh[((size_t)((b*NH + hh)*SEQ + sp))*DK + d] = (__bf16)o;
        }
  } else {
    #pragma unroll
    for (int i = 0; i < 4; ++i)
      #pragma unroll
      for (int j = 0; j < 4; ++j)
        #pragma unroll
        for (int r = 0; r < 4; ++r){
          const int m = m0 + wm*64 + i*16 + ((lane >> 4) << 2) + r;
          const int n = n0 + wn*64 + j*16 + (lane & 15);
          if (MODE == 0){
            const int b = m >> 11, sp = m & 2047, hh = n >> 6, d = n & 63;
            *(__bf16*)&Dh[(((size_t)(b*NH + hh))*DK + d)*SEQ + sp] = (__bf16)acc[i][j][r];
          } else {
            Dout[(size_t)m * DM + n] = acc[i][j][r];
          }
        }
  }
}

// ============================================================
// Causal flash attention — swapped-QK^T 32x32 in-register softmax (T12).
// Block = 4 waves; wave w owns 32 q-rows (q = qbase + lane&31).
// S^T = mfma32(A=K, B=Q): lane holds 32 of 64 kv values for its q
// (other half in lane^32). Softmax fully in-register; P -> PV B-operand
// via 16 cvt_pk + 8 shfl_xor(32). No P LDS round-trip.
// Each block processes q-tile (15-j) then j => exactly 34 kv-tiles.
// K/Vt tiles double-buffered via global_load_lds with pre-swizzled source.
// ============================================================
__global__ __launch_bounds__(256) void k_attn(const unsigned short* __restrict__ Qh,
                                              const unsigned short* __restrict__ Kh,
                                              const unsigned short* __restrict__ Vt,
                                              unsigned short* __restrict__ Ab)
{
  __shared__ uint4 ldsu[2048];   // 32 KiB: [K0 8K|V0 8K][K1 8K|V1 8K]
  char* base = (char*)ldsu;
  const int tid  = threadIdx.x;
  const int lane = tid & 63;
  const int w    = tid >> 6;
  const int l31  = lane & 31;
  const int hl   = lane >> 5;

  const int jj = blockIdx.x, bh = blockIdx.y;
  const unsigned short* Qb = Qh + (size_t)bh*(SEQ*DK);
  const unsigned short* Kb = Kh + (size_t)bh*(SEQ*DK);
  const unsigned short* Vb = Vt + (size_t)bh*(SEQ*DK);
  const int b = bh >> 4, hd = bh & 15;

  for (int pass = 0; pass < 2; ++pass){
    const int qt = pass ? jj : 15 - jj;
    const int q0 = qt * 128;
    const int qbase = q0 + w*32;

    // Q as B-operand: n=q=lane&31, k-elems d = 16t + 8*hl + e
    bf16x8 qf[4];
    #pragma unroll
    for (int t = 0; t < 4; ++t)
      qf[t] = *(const bf16x8*)(Qb + (size_t)(qbase + l31)*DK + t*16 + hl*8);

    f32x16 acc0 = (f32x16)0.0f, acc1 = (f32x16)0.0f;
    float lsum = 0.0f, mrun = -1e30f;

    const int nkt = 2*qt + 2;
    const int wqmax = qbase + 31;

    auto stage = [&](int buf, int kt){
      const int k0s = kt * 64;
      char* Kd = base + buf*16384;
      char* Vd = Kd + 8192;
      #pragma unroll
      for (int cc = 0; cc < 2; ++cc){
        const int f = cc*256 + tid;
        const int r = f >> 3, slot = f & 7;
        const int sw = ((slot ^ (r & 7)) << 3);     // element offset of 16B chunk
        gload16(Kb + (size_t)(k0s + r)*DK + sw, Kd + (cc*256 + w*64)*16);
        gload16(Vb + (size_t)r*SEQ + k0s + sw, Vd + (cc*256 + w*64)*16);
      }
    };

    if (pass) __syncthreads();     // LDS reuse across passes
    stage(0, 0);
    __syncthreads();               // drains vmcnt -> tile 0 visible
    int cur = 0;

    for (int kt = 0; kt < nkt; ++kt){
      const int k0 = kt * 64;
      if (kt + 1 < nkt) stage(cur ^ 1, kt + 1);   // prefetch overlaps compute
      if (k0 <= wqmax){
        const char* Ks = base + cur*16384;
        const char* Vs = Ks + 8192;

        // ---- S^T = K Q^T (exp2 domain): sv[m] rows kv=32m+..., col q ----
        f32x16 sv0 = (f32x16)0.0f, sv1 = (f32x16)0.0f;
        #pragma unroll
        for (int t = 0; t < 4; ++t){
          const int colb = t*32 + hl*16;
          const bf16x8 a0 = ldsw(Ks, l31, colb);
          const bf16x8 a1 = ldsw(Ks, 32 + l31, colb);
          sv0 = __builtin_amdgcn_mfma_f32_32x32x16_bf16(a0, qf[t], sv0, 0, 0, 0);
          sv1 = __builtin_amdgcn_mfma_f32_32x32x16_bf16(a1, qf[t], sv1, 0, 0, 0);
        }

        // ---- causal mask (diagonal tiles only) ----
        if (k0 + 63 > qbase){
          const int q = qbase + l31;
          #pragma unroll
          for (int j = 0; j < 16; ++j){
            const int kv = k0 + (j&3) + 8*(j>>2) + 4*hl;
            if (kv > q)      sv0[j] = -1e30f;
            if (kv + 32 > q) sv1[j] = -1e30f;
          }
        }

        // ---- online softmax, in-register (one q per lane) ----
        float mx = fmaxf(sv0[0], sv1[0]);
        #pragma unroll
        for (int j = 1; j < 16; ++j)
          mx = fmaxf(mx, fmaxf(sv0[j], sv1[j]));
        mx = fmaxf(mx, __shfl_xor(mx, 32, 64));

        if (!__all(mx - mrun <= DEFER_THR)){
          const float mnew = fmaxf(mrun, mx);
          const float corr = exp2f(mrun - mnew);
          lsum *= corr; mrun = mnew;
          #pragma unroll
          for (int j = 0; j < 16; ++j){ acc0[j] *= corr; acc1[j] *= corr; }
        }
        float psum = 0.0f;
        #pragma unroll
        for (int j = 0; j < 16; ++j){
          sv0[j] = exp2f(sv0[j] - mrun); psum += sv0[j];
          sv1[j] = exp2f(sv1[j] - mrun); psum += sv1[j];
        }
        psum += __shfl_xor(psum, 32, 64);
        lsum += psum;

        // ---- O^T += V^T P : P quads redistributed via cvt_pk + shfl(32) ----
        #pragma unroll
        for (int t = 0; t < 4; ++t){
          f32x16& s = (t < 2) ? sv0 : sv1;
          const int b0v = (t & 1) * 8;
          const unsigned int A0 = cvtpk(s[b0v+0], s[b0v+1]);
          const unsigned int A1 = cvtpk(s[b0v+2], s[b0v+3]);
          const unsigned int B0 = cvtpk(s[b0v+4], s[b0v+5]);
          const unsigned int B1 = cvtpk(s[b0v+6], s[b0v+7]);
          const unsigned int s0 = hl ? A0 : B0;
          const unsigned int s1 = hl ? A1 : B1;
          const unsigned int r0 = (unsigned int)__shfl_xor((int)s0, 32, 64);
          const unsigned int r1 = (unsigned int)__shfl_xor((int)s1, 32, 64);
          union { unsigned int u[4]; bf16x8 v; } f;
          f.u[0] = hl ? r0 : A0; f.u[1] = hl ? r1 : A1;
          f.u[2] = hl ? B0 : r0; f.u[3] = hl ? B1 : r1;
          const int colb = t*32 + hl*16;
          const bf16x8 v0 = ldsw(Vs, l31, colb);
          const bf16x8 v1 = ldsw(Vs, 32 + l31, colb);
          acc0 = __builtin_amdgcn_mfma_f32_32x32x16_bf16(v0, f.v, acc0, 0, 0, 0);
          acc1 = __builtin_amdgcn_mfma_f32_32x32x16_bf16(v1, f.v, acc1, 0, 0, 0);
        }
      }
      __syncthreads();             // compute done + prefetch vmcnt drained
      cur ^= 1;
    }

    // ---- normalize + store: lane holds O[d rows][q=lane&31] ----
    const float inv = 1.0f / lsum;
    unsigned short* orow = Ab + ((size_t)(b*SEQ + qbase + l31))*DM + hd*DK;
    #pragma unroll
    for (int mt = 0; mt < 2; ++mt){
      #pragma unroll
      for (int g = 0; g < 4; ++g){
        const f32x16& a = mt ? acc1 : acc0;
        const unsigned int u0 = cvtpk(a[4*g+0]*inv, a[4*g+1]*inv);
        const unsigned int u1 = cvtpk(a[4*g+2]*inv, a[4*g+3]*inv);
        *(unsigned long long*)(orow + mt*32 + g*8 + hl*4) =
            (unsigned long long)u0 | ((unsigned long long)u1 << 32);
      }
    }
  }
}

// ============================================================
// launch
// ============================================================
extern "C" void kernel_launch(void* const* d_in, const int* in_sizes, int n_in,
                              void* d_out, int out_size, void* d_ws, size_t ws_size,
                              hipStream_t stream)
{
  (void)in_sizes; (void)n_in; (void)out_size;
  const float* x  = (const float*)d_in[0];
  const float* wq = (const float*)d_in[1];
  const float* wk = (const float*)d_in[2];
  const float* wv = (const float*)d_in[3];
  const float* wo = (const float*)d_in[4];
  const int* pos  = (const int*)d_in[5];
  float* out = (float*)d_out;

  // workspace layout (bytes); Ab (attn out) aliases xb (x no longer needed)
  if (ws_size < 92800000u) return;   // need ~88.5 MB
  char* ws = (char*)d_ws;
  unsigned short* xb = (unsigned short*)(ws);                 // 16 MB (also Ab)
  unsigned short* wb = (unsigned short*)(ws + 16777216);      //  8 MB (Wq|Wk|Wv|Wo)
  unsigned short* Qh = (unsigned short*)(ws + 25165824);      // 16 MB [b][h][s][d]
  unsigned short* Kh = (unsigned short*)(ws + 41943040);      // 16 MB
  unsigned short* Vt = (unsigned short*)(ws + 75497472);      // 16 MB [b][h][d][s]
  float* tab         = (float*)(ws + 92274688);               // 512 KB

  k_tables  <<<256, 256, 0, stream>>>(pos, tab);
  k_convert <<<12288, 256, 0, stream>>>(x, wq, wk, wv, wo, xb, wb);
  k_gemm<0> <<<dim3(64, 8, 3), 256, 0, stream>>>(xb, wb, wb + NW, wb + 2*NW,
                                                 Qh, Kh, Vt, nullptr, tab);
  k_attn    <<<dim3(8, 64), 256, 0, stream>>>(Qh, Kh, Vt, xb);
  k_gemm<1> <<<dim3(64, 8, 1), 256, 0, stream>>>(xb, wb + 3*NW, nullptr, nullptr,
                                                 nullptr, nullptr, nullptr, out, nullptr);
}

// Round 6
// 208.730 us; speedup vs baseline: 1.5236x; 1.0775x over previous
//
#include <hip/hip_runtime.h>
#include <stdint.h>

// ---------- types ----------
typedef __attribute__((ext_vector_type(8))) __bf16 bf16x8;
typedef __attribute__((ext_vector_type(4))) float f32x4;
typedef __attribute__((ext_vector_type(16))) float f32x16;
typedef __attribute__((ext_vector_type(8))) unsigned short ushort8;

// ---------- helpers ----------
__device__ __forceinline__ unsigned short f2bf(float f){
  union { float f; unsigned int i; } v; v.f = f;
  unsigned int r = v.i + 0x7fffu + ((v.i >> 16) & 1u);   // RNE
  return (unsigned short)(r >> 16);
}
__device__ __forceinline__ void gload16(const void* g, void* l){
  __builtin_amdgcn_global_load_lds((__attribute__((address_space(1))) void*)(g),
                                   (__attribute__((address_space(3))) void*)(l),
                                   16, 0, 0);
}
__device__ __forceinline__ unsigned int cvtpk(float lo, float hi){
  unsigned int r;
  asm("v_cvt_pk_bf16_f32 %0, %1, %2" : "=v"(r) : "v"(lo), "v"(hi));
  return r;
}
// swizzled LDS read of a 16B chunk from a [64][64] bf16 tile (128B rows)
__device__ __forceinline__ bf16x8 ldsw(const char* tile, int row, int colb){
  return *(const bf16x8*)(tile + row*128 + (colb ^ ((row & 7) << 4)));
}

// ---------- constants ----------
#define SEQ   2048
#define DM    1024
#define NH    16
#define DK    64
#define BATCH 4
#define MTOT  (BATCH*SEQ)          // 8192
#define NX    (MTOT*DM)            // 8388608 elements in x
#define NW    (DM*DM)              // 1048576 per weight

#define QSCALE 0.18033688011112f   // (1/8) * log2(e)  -> softmax in exp2 domain
#define DEFER_THR 11.5f            // log2-domain rescale threshold

// ============================================================
// sin/cos table: tab[s*32+i] = {cos, sin} of pos[s]*theta^(-2i/64)
// ============================================================
__global__ __launch_bounds__(256) void k_tables(const int* __restrict__ pos,
                                                float* __restrict__ tab)
{
  const int idx = blockIdx.x * 256 + threadIdx.x;    // 65536 total
  const int s = idx >> 5, i = idx & 31;
  const float inv = __expf(-0.28782313662425575f * (float)i);
  const float a = (float)pos[s] * inv;
  tab[2*idx]   = cosf(a);
  tab[2*idx+1] = sinf(a);
}

// ============================================================
// fp32 -> bf16 convert: x (8.4M) then Wq,Wk,Wv,Wo (1M each)
// ============================================================
__global__ __launch_bounds__(256) void k_convert(
    const float* __restrict__ x,  const float* __restrict__ wq,
    const float* __restrict__ wk, const float* __restrict__ wv,
    const float* __restrict__ wo,
    unsigned short* __restrict__ xb, unsigned short* __restrict__ wb)
{
  const long long tid = (long long)blockIdx.x * 256 + threadIdx.x;
  const long long e = tid * 4;
  const float* src; unsigned short* dst;
  if (e < NX) { src = x + e; dst = xb + e; }
  else {
    long long j = e - NX;
    int seg = (int)(j >> 20);            // /1048576
    long long off = j & 1048575;
    src = (seg==0?wq:seg==1?wk:seg==2?wv:wo) + off;
    dst = wb + (size_t)seg*NW + off;
  }
  float4 v = *(const float4*)src;
  unsigned long long pk =  (unsigned long long)f2bf(v.x)
                        | ((unsigned long long)f2bf(v.y) << 16)
                        | ((unsigned long long)f2bf(v.z) << 32)
                        | ((unsigned long long)f2bf(v.w) << 48);
  *(unsigned long long*)dst = pk;
}

// ============================================================
// NT GEMM: C[M=8192][N=1024] = A[M][K=1024] * W[N][K]^T  (bf16 MFMA)
// 128x128 tile, BK=32, 4 waves (2x2), m97-style global_load_lds staging.
// MODE 0: z in {0,1,2} -> W{q,k,v}; z<2 apply RoPE in epilogue (Q also
//         scaled by QSCALE) and write bf16 [b][h][s][d]; z==2 (V) writes
//         bf16 TRANSPOSED [b][h][d][s].
// MODE 1: write fp32 to Dout [M][N]
// ============================================================
#define BK 32
#define NTK (DM/BK)   // 32

template<int MODE>
__global__ __launch_bounds__(256) void k_gemm(
    const unsigned short* __restrict__ A,
    const unsigned short* __restrict__ W0,
    const unsigned short* __restrict__ W1,
    const unsigned short* __restrict__ W2,
    unsigned short* __restrict__ D0,
    unsigned short* __restrict__ D1,
    unsigned short* __restrict__ D2,
    float* __restrict__ Dout,
    const float* __restrict__ tab)
{
  __shared__ __attribute__((aligned(16))) unsigned short As[2][128*BK];
  __shared__ __attribute__((aligned(16))) unsigned short Bs[2][128*BK];
  const int tid  = threadIdx.x;
  const int lane = tid & 63;
  const int wv   = tid >> 6;
  const int wm = wv >> 1, wn = wv & 1;
  const int m0 = blockIdx.x * 128;
  const int n0 = blockIdx.y * 128;

  const unsigned short* W;
  unsigned short* Dh = nullptr;
  bool vtr = false;
  if (MODE == 0) {
    const int z = blockIdx.z;
    W  = (z == 0) ? W0 : (z == 1) ? W1 : W2;
    Dh = (z == 0) ? D0 : (z == 1) ? D1 : D2;
    vtr = (z == 2);
  } else {
    W = W0;
  }

  f32x4 acc[4][4];
  #pragma unroll
  for (int i = 0; i < 4; ++i)
    #pragma unroll
    for (int j = 0; j < 4; ++j)
      acc[i][j] = (f32x4)0.0f;

  auto stage = [&](int buf, int t){
    const int k0 = t * BK;
    #pragma unroll
    for (int cc = 0; cc < 2; ++cc){
      const int f = cc*256 + tid;
      const int row = f >> 2, kc = f & 3;
      gload16(A + (size_t)(m0 + row)*DM + k0 + kc*8,
              (char*)&As[buf][0] + (cc*256 + wv*64)*16);
      gload16(W + (size_t)(n0 + row)*DM + k0 + kc*8,
              (char*)&Bs[buf][0] + (cc*256 + wv*64)*16);
    }
  };

  stage(0, 0);
  __syncthreads();
  int cur = 0;
  for (int t = 0; t < NTK; ++t){
    if (t + 1 < NTK) stage(cur ^ 1, t + 1);
    const char* Ab_ = (const char*)&As[cur][0];
    const char* Bb_ = (const char*)&Bs[cur][0];
    bf16x8 af[4], bfr[4];
    #pragma unroll
    for (int i = 0; i < 4; ++i){
      af[i]  = *(const bf16x8*)(Ab_ + (wm*64 + i*16 + (lane & 15))*64 + ((lane >> 4) << 4));
      bfr[i] = *(const bf16x8*)(Bb_ + (wn*64 + i*16 + (lane & 15))*64 + ((lane >> 4) << 4));
    }
    #pragma unroll
    for (int i = 0; i < 4; ++i)
      #pragma unroll
      for (int j = 0; j < 4; ++j)
        acc[i][j] = __builtin_amdgcn_mfma_f32_16x16x32_bf16(af[i], bfr[j], acc[i][j], 0, 0, 0);
    __syncthreads();
    cur ^= 1;
  }

  // epilogue: C row = (lane>>4)*4+r, col = lane&15 (verified m89/m91 layout)
  if (MODE == 0 && !vtr){
    // fused RoPE: pairs (2i,2i+1) of d live in adjacent lanes -> shfl_xor(1)
    const float scale = (blockIdx.z == 0) ? QSCALE : 1.0f;
    #pragma unroll
    for (int i = 0; i < 4; ++i)
      #pragma unroll
      for (int j = 0; j < 4; ++j)
        #pragma unroll
        for (int r = 0; r < 4; ++r){
          const int m = m0 + wm*64 + i*16 + ((lane >> 4) << 2) + r;
          const int n = n0 + wn*64 + j*16 + (lane & 15);
          const float v  = acc[i][j][r];
          const float vp = __shfl_xor(v, 1, 64);
          const int sp = m & 2047, d = n & 63;
          const float2 cs = ((const float2*)tab)[sp*32 + (d >> 1)];
          const float o = ((n & 1) ? (cs.y*vp + cs.x*v) : (cs.x*v - cs.y*vp)) * scale;
          const int b = m >> 11, hh = n >> 6;
          *(__bf16*)&Dh[((size_t)((b*NH + hh)*SEQ + sp))*DK + d] = (__bf16)o;
        }
  } else {
    #pragma unroll
    for (int i = 0; i < 4; ++i)
      #pragma unroll
      for (int j = 0; j < 4; ++j)
        #pragma unroll
        for (int r = 0; r < 4; ++r){
          const int m = m0 + wm*64 + i*16 + ((lane >> 4) << 2) + r;
          const int n = n0 + wn*64 + j*16 + (lane & 15);
          if (MODE == 0){
            const int b = m >> 11, sp = m & 2047, hh = n >> 6, d = n & 63;
            *(__bf16*)&Dh[(((size_t)(b*NH + hh))*DK + d)*SEQ + sp] = (__bf16)acc[i][j][r];
          } else {
            Dout[(size_t)m * DM + n] = acc[i][j][r];
          }
        }
  }
}

// ============================================================
// Causal flash attention — swapped-QK^T 32x32 in-register softmax,
// kv-split dual-group blocks (8 waves, 512 threads).
// Waves 0-3 (group0) process kv-half-0, waves 4-7 (group1) kv-half-1
// of the SAME 128 q-rows; per pass qt both halves have exactly qt+1
// tiles -> identical barrier trip counts. Block does q-tile (15-j)
// then j => 17 staged tiles per group (perfect balance).
// After kv loop: group1 writes (acc,m,l) to LDS, group0 merges
// (standard flash combine) and stores. Tree-reduced max/psum.
// ============================================================
__global__ __launch_bounds__(512, 4) void k_attn(const unsigned short* __restrict__ Qh,
                                                 const unsigned short* __restrict__ Kh,
                                                 const unsigned short* __restrict__ Vt,
                                                 unsigned short* __restrict__ Ab)
{
  __shared__ uint4 ldsu[4096];   // 64 KiB: per-group [K0 8K|V0 8K][K1 8K|V1 8K]
  char* base = (char*)ldsu;
  const int tid  = threadIdx.x;
  const int lane = tid & 63;
  const int w    = tid >> 6;     // 0..7
  const int ww   = w & 3;        // wave-in-group
  const int g    = w >> 2;       // kv-half group
  const int tl   = tid & 255;    // thread-in-group
  const int l31  = lane & 31;
  const int hl   = lane >> 5;
  char* gb = base + g*32768;

  const int jj = blockIdx.x, bh = blockIdx.y;
  const unsigned short* Qb = Qh + (size_t)bh*(SEQ*DK);
  const unsigned short* Kb = Kh + (size_t)bh*(SEQ*DK);
  const unsigned short* Vb = Vt + (size_t)bh*(SEQ*DK);
  const int b = bh >> 4, hd = bh & 15;

  for (int pass = 0; pass < 2; ++pass){
    const int qt = pass ? jj : 15 - jj;
    const int q0 = qt * 128;
    const int qbase = q0 + ww*32;

    // Q as B-operand: n=q=lane&31, k-elems d = 16t + 8*hl + e
    bf16x8 qf[4];
    #pragma unroll
    for (int t = 0; t < 4; ++t)
      qf[t] = *(const bf16x8*)(Qb + (size_t)(qbase + l31)*DK + t*16 + hl*8);

    f32x16 acc0 = (f32x16)0.0f, acc1 = (f32x16)0.0f;
    float lsum = 0.0f, mrun = -1e30f;

    const int nk = qt + 1;           // tiles per group
    const int tbase = g * nk;        // group's first kv-tile
    const int wqmax = qbase + 31;

    auto stage = [&](int buf, int ktile){
      const int k0s = ktile * 64;
      char* Kd = gb + buf*16384;
      char* Vd = Kd + 8192;
      #pragma unroll
      for (int cc = 0; cc < 2; ++cc){
        const int f = cc*256 + tl;
        const int r = f >> 3, slot = f & 7;
        const int sw = ((slot ^ (r & 7)) << 3);     // element offset of 16B chunk
        gload16(Kb + (size_t)(k0s + r)*DK + sw, Kd + (cc*256 + ww*64)*16);
        gload16(Vb + (size_t)r*SEQ + k0s + sw, Vd + (cc*256 + ww*64)*16);
      }
    };

    if (pass) __syncthreads();     // LDS reuse across passes (also guards combine reads)
    stage(0, tbase);
    __syncthreads();               // drains vmcnt -> tile 0 visible
    int cur = 0;

    for (int kt = 0; kt < nk; ++kt){
      const int k0 = (tbase + kt) * 64;
      if (kt + 1 < nk) stage(cur ^ 1, tbase + kt + 1);   // prefetch overlaps compute
      if (k0 <= wqmax){
        const char* Ks = gb + cur*16384;
        const char* Vs = Ks + 8192;

        // ---- S^T = K Q^T (exp2 domain): sv[m] rows kv=32m+..., col q ----
        f32x16 sv0 = (f32x16)0.0f, sv1 = (f32x16)0.0f;
        #pragma unroll
        for (int t = 0; t < 4; ++t){
          const int colb = t*32 + hl*16;
          const bf16x8 a0 = ldsw(Ks, l31, colb);
          const bf16x8 a1 = ldsw(Ks, 32 + l31, colb);
          sv0 = __builtin_amdgcn_mfma_f32_32x32x16_bf16(a0, qf[t], sv0, 0, 0, 0);
          sv1 = __builtin_amdgcn_mfma_f32_32x32x16_bf16(a1, qf[t], sv1, 0, 0, 0);
        }

        // ---- causal mask (diagonal tiles only) ----
        if (k0 + 63 > qbase){
          const int q = qbase + l31;
          #pragma unroll
          for (int j = 0; j < 16; ++j){
            const int kv = k0 + (j&3) + 8*(j>>2) + 4*hl;
            if (kv > q)      sv0[j] = -1e30f;
            if (kv + 32 > q) sv1[j] = -1e30f;
          }
        }

        // ---- online softmax, in-register, tree-reduced ----
        float tm[8];
        #pragma unroll
        for (int j = 0; j < 8; ++j)
          tm[j] = fmaxf(fmaxf(sv0[j], sv0[j+8]), fmaxf(sv1[j], sv1[j+8]));
        #pragma unroll
        for (int off = 4; off; off >>= 1)
          #pragma unroll
          for (int j = 0; j < off; ++j)
            tm[j] = fmaxf(tm[j], tm[j+off]);
        float mx = fmaxf(tm[0], __shfl_xor(tm[0], 32, 64));

        if (!__all(mx - mrun <= DEFER_THR)){
          const float mnew = fmaxf(mrun, mx);
          const float corr = exp2f(mrun - mnew);
          lsum *= corr; mrun = mnew;
          #pragma unroll
          for (int j = 0; j < 16; ++j){ acc0[j] *= corr; acc1[j] *= corr; }
        }
        #pragma unroll
        for (int j = 0; j < 16; ++j){
          sv0[j] = exp2f(sv0[j] - mrun);
          sv1[j] = exp2f(sv1[j] - mrun);
        }
        float ts[8];
        #pragma unroll
        for (int j = 0; j < 8; ++j)
          ts[j] = (sv0[j] + sv0[j+8]) + (sv1[j] + sv1[j+8]);
        #pragma unroll
        for (int off = 4; off; off >>= 1)
          #pragma unroll
          for (int j = 0; j < off; ++j)
            ts[j] += ts[j+off];
        lsum += ts[0] + __shfl_xor(ts[0], 32, 64);

        // ---- O^T += V^T P : P quads redistributed via cvt_pk + shfl(32) ----
        #pragma unroll
        for (int t = 0; t < 4; ++t){
          f32x16& s = (t < 2) ? sv0 : sv1;
          const int b0v = (t & 1) * 8;
          const unsigned int A0 = cvtpk(s[b0v+0], s[b0v+1]);
          const unsigned int A1 = cvtpk(s[b0v+2], s[b0v+3]);
          const unsigned int B0 = cvtpk(s[b0v+4], s[b0v+5]);
          const unsigned int B1 = cvtpk(s[b0v+6], s[b0v+7]);
          const unsigned int s0 = hl ? A0 : B0;
          const unsigned int s1 = hl ? A1 : B1;
          const unsigned int r0 = (unsigned int)__shfl_xor((int)s0, 32, 64);
          const unsigned int r1 = (unsigned int)__shfl_xor((int)s1, 32, 64);
          union { unsigned int u[4]; bf16x8 v; } f;
          f.u[0] = hl ? r0 : A0; f.u[1] = hl ? r1 : A1;
          f.u[2] = hl ? B0 : r0; f.u[3] = hl ? B1 : r1;
          const int colb = t*32 + hl*16;
          const bf16x8 v0 = ldsw(Vs, l31, colb);
          const bf16x8 v1 = ldsw(Vs, 32 + l31, colb);
          acc0 = __builtin_amdgcn_mfma_f32_32x32x16_bf16(v0, f.v, acc0, 0, 0, 0);
          acc1 = __builtin_amdgcn_mfma_f32_32x32x16_bf16(v1, f.v, acc1, 0, 0, 0);
        }
      }
      __syncthreads();             // compute done + prefetch vmcnt drained
      cur ^= 1;
    }

    // ---- combine halves: group1 -> LDS, group0 merges + stores ----
    if (g == 1){
      char* cw = base + ww*9216 + lane*144;
      #pragma unroll
      for (int q4 = 0; q4 < 4; ++q4){
        *(f32x4*)(cw + q4*16)      = (f32x4){acc0[4*q4], acc0[4*q4+1], acc0[4*q4+2], acc0[4*q4+3]};
        *(f32x4*)(cw + 64 + q4*16) = (f32x4){acc1[4*q4], acc1[4*q4+1], acc1[4*q4+2], acc1[4*q4+3]};
      }
      *(float*)(cw + 128) = mrun;
      *(float*)(cw + 132) = lsum;
    }
    __syncthreads();
    if (g == 0){
      const char* cr = base + ww*9216 + lane*144;
      const float m1 = *(const float*)(cr + 128);
      const float l1 = *(const float*)(cr + 132);
      const float mm = fmaxf(mrun, m1);
      const float c0 = exp2f(mrun - mm);
      const float c1 = exp2f(m1 - mm);
      const float linv = 1.0f / (lsum*c0 + l1*c1);
      const float f0 = c0 * linv, f1 = c1 * linv;
      unsigned short* orow = Ab + ((size_t)(b*SEQ + qbase + l31))*DM + hd*DK;
      #pragma unroll
      for (int mt = 0; mt < 2; ++mt){
        #pragma unroll
        for (int g4 = 0; g4 < 4; ++g4){
          const f32x16& a = mt ? acc1 : acc0;
          const f32x4 o = *(const f32x4*)(cr + mt*64 + g4*16);
          const unsigned int u0 = cvtpk(a[4*g4+0]*f0 + o[0]*f1, a[4*g4+1]*f0 + o[1]*f1);
          const unsigned int u1 = cvtpk(a[4*g4+2]*f0 + o[2]*f1, a[4*g4+3]*f0 + o[3]*f1);
          *(unsigned long long*)(orow + mt*32 + g4*8 + hl*4) =
              (unsigned long long)u0 | ((unsigned long long)u1 << 32);
        }
      }
    }
  }
}

// ============================================================
// launch
// ============================================================
extern "C" void kernel_launch(void* const* d_in, const int* in_sizes, int n_in,
                              void* d_out, int out_size, void* d_ws, size_t ws_size,
                              hipStream_t stream)
{
  (void)in_sizes; (void)n_in; (void)out_size;
  const float* x  = (const float*)d_in[0];
  const float* wq = (const float*)d_in[1];
  const float* wk = (const float*)d_in[2];
  const float* wv = (const float*)d_in[3];
  const float* wo = (const float*)d_in[4];
  const int* pos  = (const int*)d_in[5];
  float* out = (float*)d_out;

  // workspace layout (bytes); Ab (attn out) aliases xb (x no longer needed)
  if (ws_size < 92800000u) return;   // need ~88.5 MB
  char* ws = (char*)d_ws;
  unsigned short* xb = (unsigned short*)(ws);                 // 16 MB (also Ab)
  unsigned short* wb = (unsigned short*)(ws + 16777216);      //  8 MB (Wq|Wk|Wv|Wo)
  unsigned short* Qh = (unsigned short*)(ws + 25165824);      // 16 MB [b][h][s][d]
  unsigned short* Kh = (unsigned short*)(ws + 41943040);      // 16 MB
  unsigned short* Vt = (unsigned short*)(ws + 75497472);      // 16 MB [b][h][d][s]
  float* tab         = (float*)(ws + 92274688);               // 512 KB

  k_tables  <<<256, 256, 0, stream>>>(pos, tab);
  k_convert <<<12288, 256, 0, stream>>>(x, wq, wk, wv, wo, xb, wb);
  k_gemm<0> <<<dim3(64, 8, 3), 256, 0, stream>>>(xb, wb, wb + NW, wb + 2*NW,
                                                 Qh, Kh, Vt, nullptr, tab);
  k_attn    <<<dim3(8, 64), 512, 0, stream>>>(Qh, Kh, Vt, xb);
  k_gemm<1> <<<dim3(64, 8, 1), 256, 0, stream>>>(xb, wb + 3*NW, nullptr, nullptr,
                                                 nullptr, nullptr, nullptr, out, nullptr);
}

// Round 7
// 196.796 us; speedup vs baseline: 1.6160x; 1.0606x over previous
//
#include <hip/hip_runtime.h>
#include <stdint.h>

// ---------- types ----------
typedef __attribute__((ext_vector_type(8))) __bf16 bf16x8;
typedef __attribute__((ext_vector_type(4))) float f32x4;
typedef __attribute__((ext_vector_type(16))) float f32x16;
typedef __attribute__((ext_vector_type(8))) unsigned short ushort8;

// ---------- helpers ----------
__device__ __forceinline__ unsigned short f2bf(float f){
  union { float f; unsigned int i; } v; v.f = f;
  unsigned int r = v.i + 0x7fffu + ((v.i >> 16) & 1u);   // RNE
  return (unsigned short)(r >> 16);
}
__device__ __forceinline__ void gload16(const void* g, void* l){
  __builtin_amdgcn_global_load_lds((__attribute__((address_space(1))) void*)(g),
                                   (__attribute__((address_space(3))) void*)(l),
                                   16, 0, 0);
}
__device__ __forceinline__ unsigned int cvtpk(float lo, float hi){
  unsigned int r;
  asm("v_cvt_pk_bf16_f32 %0, %1, %2" : "=v"(r) : "v"(lo), "v"(hi));
  return r;
}
// swizzled LDS read of a 16B chunk from a [64][64] bf16 tile (128B rows)
__device__ __forceinline__ bf16x8 ldsw(const char* tile, int row, int colb){
  return *(const bf16x8*)(tile + row*128 + (colb ^ ((row & 7) << 4)));
}

// ---------- constants ----------
#define SEQ   2048
#define DM    1024
#define NH    16
#define DK    64
#define BATCH 4
#define MTOT  (BATCH*SEQ)          // 8192
#define NX    (MTOT*DM)            // 8388608 elements in x
#define NW    (DM*DM)              // 1048576 per weight

#define QSCALE 0.18033688011112f   // (1/8) * log2(e)  -> softmax in exp2 domain
#define DEFER_THR 11.5f            // log2-domain rescale threshold

// ============================================================
// sin/cos table: tab[s*32+i] = {cos, sin} of pos[s]*theta^(-2i/64)
// ============================================================
__global__ __launch_bounds__(256) void k_tables(const int* __restrict__ pos,
                                                float* __restrict__ tab)
{
  const int idx = blockIdx.x * 256 + threadIdx.x;    // 65536 total
  const int s = idx >> 5, i = idx & 31;
  const float inv = __expf(-0.28782313662425575f * (float)i);
  const float a = (float)pos[s] * inv;
  tab[2*idx]   = cosf(a);
  tab[2*idx+1] = sinf(a);
}

// ============================================================
// fp32 -> bf16 convert: x (8.4M) then Wq,Wk,Wv,Wo (1M each)
// ============================================================
__global__ __launch_bounds__(256) void k_convert(
    const float* __restrict__ x,  const float* __restrict__ wq,
    const float* __restrict__ wk, const float* __restrict__ wv,
    const float* __restrict__ wo,
    unsigned short* __restrict__ xb, unsigned short* __restrict__ wb)
{
  const long long tid = (long long)blockIdx.x * 256 + threadIdx.x;
  const long long e = tid * 4;
  const float* src; unsigned short* dst;
  if (e < NX) { src = x + e; dst = xb + e; }
  else {
    long long j = e - NX;
    int seg = (int)(j >> 20);            // /1048576
    long long off = j & 1048575;
    src = (seg==0?wq:seg==1?wk:seg==2?wv:wo) + off;
    dst = wb + (size_t)seg*NW + off;
  }
  float4 v = *(const float4*)src;
  unsigned long long pk =  (unsigned long long)f2bf(v.x)
                        | ((unsigned long long)f2bf(v.y) << 16)
                        | ((unsigned long long)f2bf(v.z) << 32)
                        | ((unsigned long long)f2bf(v.w) << 48);
  *(unsigned long long*)dst = pk;
}

// ============================================================
// NT GEMM: C[M=8192][N] = A[M][K=1024] * W[N][K]^T  (bf16 MFMA)
// 256x128 tile, BK=32, 8 waves (4M x 2N), per-wave 64x64 output.
// 2-phase double-buffered global_load_lds staging. 48 KB LDS ->
// 3 blocks/CU; grid = exact multiples of 256 CUs.
// MODE 0: z in {0,1,2} -> W{q,k,v}; z<2 apply RoPE in epilogue (Q also
//         scaled by QSCALE) and write bf16 [b][h][s][d]; z==2 (V) writes
//         bf16 TRANSPOSED [b][h][d][s].
// MODE 1: write fp32 to Dout [M][N]
// ============================================================
#define BK 32
#define NTK (DM/BK)   // 32

template<int MODE>
__global__ __launch_bounds__(512, 3) void k_gemm(
    const unsigned short* __restrict__ A,
    const unsigned short* __restrict__ Wb,
    unsigned short* __restrict__ D0,
    unsigned short* __restrict__ D1,
    unsigned short* __restrict__ D2,
    float* __restrict__ Dout,
    const float* __restrict__ tab)
{
  __shared__ __attribute__((aligned(16))) unsigned short As[2][256*BK];  // 32 KB
  __shared__ __attribute__((aligned(16))) unsigned short Bs[2][128*BK];  // 16 KB
  const int tid  = threadIdx.x;
  const int lane = tid & 63;
  const int w    = tid >> 6;          // 0..7
  const int wm = w >> 1, wn = w & 1;  // 4M x 2N
  const int m0 = blockIdx.x * 256;
  const int n0 = blockIdx.y * 128;

  const int z = (MODE == 0) ? blockIdx.z : 0;
  const unsigned short* W = Wb + (size_t)z * NW;
  unsigned short* Dh = (MODE == 0) ? ((z == 0) ? D0 : (z == 1) ? D1 : D2) : nullptr;
  const bool vtr = (MODE == 0) && (z == 2);

  f32x4 acc[4][4];
  #pragma unroll
  for (int i = 0; i < 4; ++i)
    #pragma unroll
    for (int j = 0; j < 4; ++j)
      acc[i][j] = (f32x4)0.0f;

  auto stage = [&](int buf, int t){
    const int k0 = t * BK;
    // A tile: 256x32 (32 KB) = 2 sweeps of 512 threads x 16B
    #pragma unroll
    for (int cc = 0; cc < 2; ++cc){
      const int f = cc*512 + tid;
      const int row = f >> 2, kc = f & 3;
      gload16(A + (size_t)(m0 + row)*DM + k0 + kc*8,
              (char*)&As[buf][0] + (cc*512 + w*64)*16);
    }
    // B tile: 128x32 (8 KB) = 1 sweep
    {
      const int row = tid >> 2, kc = tid & 3;
      gload16(W + (size_t)(n0 + row)*DM + k0 + kc*8,
              (char*)&Bs[buf][0] + (w*64)*16);
    }
  };

  stage(0, 0);
  __syncthreads();
  int cur = 0;
  for (int t = 0; t < NTK; ++t){
    if (t + 1 < NTK) stage(cur ^ 1, t + 1);
    const char* Ab_ = (const char*)&As[cur][0];
    const char* Bb_ = (const char*)&Bs[cur][0];
    bf16x8 af[4], bfr[4];
    #pragma unroll
    for (int i = 0; i < 4; ++i){
      af[i]  = *(const bf16x8*)(Ab_ + (wm*64 + i*16 + (lane & 15))*64 + ((lane >> 4) << 4));
      bfr[i] = *(const bf16x8*)(Bb_ + (wn*64 + i*16 + (lane & 15))*64 + ((lane >> 4) << 4));
    }
    #pragma unroll
    for (int i = 0; i < 4; ++i)
      #pragma unroll
      for (int j = 0; j < 4; ++j)
        acc[i][j] = __builtin_amdgcn_mfma_f32_16x16x32_bf16(af[i], bfr[j], acc[i][j], 0, 0, 0);
    __syncthreads();
    cur ^= 1;
  }

  // epilogue: C row = (lane>>4)*4+r, col = lane&15 (verified m89/m91 layout)
  if (MODE == 0 && !vtr){
    // fused RoPE: pairs (2i,2i+1) of d live in adjacent lanes -> shfl_xor(1)
    const float scale = (z == 0) ? QSCALE : 1.0f;
    #pragma unroll
    for (int i = 0; i < 4; ++i)
      #pragma unroll
      for (int j = 0; j < 4; ++j)
        #pragma unroll
        for (int r = 0; r < 4; ++r){
          const int m = m0 + wm*64 + i*16 + ((lane >> 4) << 2) + r;
          const int n = n0 + wn*64 + j*16 + (lane & 15);
          const float v  = acc[i][j][r];
          const float vp = __shfl_xor(v, 1, 64);
          const int sp = m & 2047, d = n & 63;
          const float2 cs = ((const float2*)tab)[sp*32 + (d >> 1)];
          const float o = ((n & 1) ? (cs.y*vp + cs.x*v) : (cs.x*v - cs.y*vp)) * scale;
          const int b = m >> 11, hh = n >> 6;
          *(__bf16*)&Dh[((size_t)((b*NH + hh)*SEQ + sp))*DK + d] = (__bf16)o;
        }
  } else {
    #pragma unroll
    for (int i = 0; i < 4; ++i)
      #pragma unroll
      for (int j = 0; j < 4; ++j)
        #pragma unroll
        for (int r = 0; r < 4; ++r){
          const int m = m0 + wm*64 + i*16 + ((lane >> 4) << 2) + r;
          const int n = n0 + wn*64 + j*16 + (lane & 15);
          if (MODE == 0){
            const int b = m >> 11, sp = m & 2047, hh = n >> 6, d = n & 63;
            *(__bf16*)&Dh[(((size_t)(b*NH + hh))*DK + d)*SEQ + sp] = (__bf16)acc[i][j][r];
          } else {
            Dout[(size_t)m * DM + n] = acc[i][j][r];
          }
        }
  }
}

// ============================================================
// Causal flash attention — swapped-QK^T 32x32 in-register softmax,
// kv-split dual-group blocks (8 waves, 512 threads).
// Waves 0-3 (group0) process kv-half-0, waves 4-7 (group1) kv-half-1
// of the SAME 128 q-rows; per pass qt both halves have exactly qt+1
// tiles -> identical barrier trip counts. Block does q-tile (15-j)
// then j => 17 staged tiles per group (perfect balance).
// After kv loop: group1 writes (acc,m,l) to LDS, group0 merges
// (standard flash combine) and stores. Tree-reduced max/psum.
// ============================================================
__global__ __launch_bounds__(512, 4) void k_attn(const unsigned short* __restrict__ Qh,
                                                 const unsigned short* __restrict__ Kh,
                                                 const unsigned short* __restrict__ Vt,
                                                 unsigned short* __restrict__ Ab)
{
  __shared__ uint4 ldsu[4096];   // 64 KiB: per-group [K0 8K|V0 8K][K1 8K|V1 8K]
  char* base = (char*)ldsu;
  const int tid  = threadIdx.x;
  const int lane = tid & 63;
  const int w    = tid >> 6;     // 0..7
  const int ww   = w & 3;        // wave-in-group
  const int g    = w >> 2;       // kv-half group
  const int tl   = tid & 255;    // thread-in-group
  const int l31  = lane & 31;
  const int hl   = lane >> 5;
  char* gb = base + g*32768;

  const int jj = blockIdx.x, bh = blockIdx.y;
  const unsigned short* Qb = Qh + (size_t)bh*(SEQ*DK);
  const unsigned short* Kb = Kh + (size_t)bh*(SEQ*DK);
  const unsigned short* Vb = Vt + (size_t)bh*(SEQ*DK);
  const int b = bh >> 4, hd = bh & 15;

  for (int pass = 0; pass < 2; ++pass){
    const int qt = pass ? jj : 15 - jj;
    const int q0 = qt * 128;
    const int qbase = q0 + ww*32;

    // Q as B-operand: n=q=lane&31, k-elems d = 16t + 8*hl + e
    bf16x8 qf[4];
    #pragma unroll
    for (int t = 0; t < 4; ++t)
      qf[t] = *(const bf16x8*)(Qb + (size_t)(qbase + l31)*DK + t*16 + hl*8);

    f32x16 acc0 = (f32x16)0.0f, acc1 = (f32x16)0.0f;
    float lsum = 0.0f, mrun = -1e30f;

    const int nk = qt + 1;           // tiles per group
    const int tbase = g * nk;        // group's first kv-tile
    const int wqmax = qbase + 31;

    auto stage = [&](int buf, int ktile){
      const int k0s = ktile * 64;
      char* Kd = gb + buf*16384;
      char* Vd = Kd + 8192;
      #pragma unroll
      for (int cc = 0; cc < 2; ++cc){
        const int f = cc*256 + tl;
        const int r = f >> 3, slot = f & 7;
        const int sw = ((slot ^ (r & 7)) << 3);     // element offset of 16B chunk
        gload16(Kb + (size_t)(k0s + r)*DK + sw, Kd + (cc*256 + ww*64)*16);
        gload16(Vb + (size_t)r*SEQ + k0s + sw, Vd + (cc*256 + ww*64)*16);
      }
    };

    if (pass) __syncthreads();     // LDS reuse across passes (also guards combine reads)
    stage(0, tbase);
    __syncthreads();               // drains vmcnt -> tile 0 visible
    int cur = 0;

    for (int kt = 0; kt < nk; ++kt){
      const int k0 = (tbase + kt) * 64;
      if (kt + 1 < nk) stage(cur ^ 1, tbase + kt + 1);   // prefetch overlaps compute
      if (k0 <= wqmax){
        const char* Ks = gb + cur*16384;
        const char* Vs = Ks + 8192;

        // ---- S^T = K Q^T (exp2 domain): sv[m] rows kv=32m+..., col q ----
        f32x16 sv0 = (f32x16)0.0f, sv1 = (f32x16)0.0f;
        #pragma unroll
        for (int t = 0; t < 4; ++t){
          const int colb = t*32 + hl*16;
          const bf16x8 a0 = ldsw(Ks, l31, colb);
          const bf16x8 a1 = ldsw(Ks, 32 + l31, colb);
          sv0 = __builtin_amdgcn_mfma_f32_32x32x16_bf16(a0, qf[t], sv0, 0, 0, 0);
          sv1 = __builtin_amdgcn_mfma_f32_32x32x16_bf16(a1, qf[t], sv1, 0, 0, 0);
        }

        // ---- causal mask (diagonal tiles only) ----
        if (k0 + 63 > qbase){
          const int q = qbase + l31;
          #pragma unroll
          for (int j = 0; j < 16; ++j){
            const int kv = k0 + (j&3) + 8*(j>>2) + 4*hl;
            if (kv > q)      sv0[j] = -1e30f;
            if (kv + 32 > q) sv1[j] = -1e30f;
          }
        }

        // ---- online softmax, in-register, tree-reduced ----
        float tm[8];
        #pragma unroll
        for (int j = 0; j < 8; ++j)
          tm[j] = fmaxf(fmaxf(sv0[j], sv0[j+8]), fmaxf(sv1[j], sv1[j+8]));
        #pragma unroll
        for (int off = 4; off; off >>= 1)
          #pragma unroll
          for (int j = 0; j < off; ++j)
            tm[j] = fmaxf(tm[j], tm[j+off]);
        float mx = fmaxf(tm[0], __shfl_xor(tm[0], 32, 64));

        if (!__all(mx - mrun <= DEFER_THR)){
          const float mnew = fmaxf(mrun, mx);
          const float corr = exp2f(mrun - mnew);
          lsum *= corr; mrun = mnew;
          #pragma unroll
          for (int j = 0; j < 16; ++j){ acc0[j] *= corr; acc1[j] *= corr; }
        }
        #pragma unroll
        for (int j = 0; j < 16; ++j){
          sv0[j] = exp2f(sv0[j] - mrun);
          sv1[j] = exp2f(sv1[j] - mrun);
        }
        float ts[8];
        #pragma unroll
        for (int j = 0; j < 8; ++j)
          ts[j] = (sv0[j] + sv0[j+8]) + (sv1[j] + sv1[j+8]);
        #pragma unroll
        for (int off = 4; off; off >>= 1)
          #pragma unroll
          for (int j = 0; j < off; ++j)
            ts[j] += ts[j+off];
        lsum += ts[0] + __shfl_xor(ts[0], 32, 64);

        // ---- O^T += V^T P : P quads redistributed via cvt_pk + shfl(32) ----
        #pragma unroll
        for (int t = 0; t < 4; ++t){
          f32x16& s = (t < 2) ? sv0 : sv1;
          const int b0v = (t & 1) * 8;
          const unsigned int A0 = cvtpk(s[b0v+0], s[b0v+1]);
          const unsigned int A1 = cvtpk(s[b0v+2], s[b0v+3]);
          const unsigned int B0 = cvtpk(s[b0v+4], s[b0v+5]);
          const unsigned int B1 = cvtpk(s[b0v+6], s[b0v+7]);
          const unsigned int s0 = hl ? A0 : B0;
          const unsigned int s1 = hl ? A1 : B1;
          const unsigned int r0 = (unsigned int)__shfl_xor((int)s0, 32, 64);
          const unsigned int r1 = (unsigned int)__shfl_xor((int)s1, 32, 64);
          union { unsigned int u[4]; bf16x8 v; } f;
          f.u[0] = hl ? r0 : A0; f.u[1] = hl ? r1 : A1;
          f.u[2] = hl ? B0 : r0; f.u[3] = hl ? B1 : r1;
          const int colb = t*32 + hl*16;
          const bf16x8 v0 = ldsw(Vs, l31, colb);
          const bf16x8 v1 = ldsw(Vs, 32 + l31, colb);
          acc0 = __builtin_amdgcn_mfma_f32_32x32x16_bf16(v0, f.v, acc0, 0, 0, 0);
          acc1 = __builtin_amdgcn_mfma_f32_32x32x16_bf16(v1, f.v, acc1, 0, 0, 0);
        }
      }
      __syncthreads();             // compute done + prefetch vmcnt drained
      cur ^= 1;
    }

    // ---- combine halves: group1 -> LDS, group0 merges + stores ----
    if (g == 1){
      char* cw = base + ww*9216 + lane*144;
      #pragma unroll
      for (int q4 = 0; q4 < 4; ++q4){
        *(f32x4*)(cw + q4*16)      = (f32x4){acc0[4*q4], acc0[4*q4+1], acc0[4*q4+2], acc0[4*q4+3]};
        *(f32x4*)(cw + 64 + q4*16) = (f32x4){acc1[4*q4], acc1[4*q4+1], acc1[4*q4+2], acc1[4*q4+3]};
      }
      *(float*)(cw + 128) = mrun;
      *(float*)(cw + 132) = lsum;
    }
    __syncthreads();
    if (g == 0){
      const char* cr = base + ww*9216 + lane*144;
      const float m1 = *(const float*)(cr + 128);
      const float l1 = *(const float*)(cr + 132);
      const float mm = fmaxf(mrun, m1);
      const float c0 = exp2f(mrun - mm);
      const float c1 = exp2f(m1 - mm);
      const float linv = 1.0f / (lsum*c0 + l1*c1);
      const float f0 = c0 * linv, f1 = c1 * linv;
      unsigned short* orow = Ab + ((size_t)(b*SEQ + qbase + l31))*DM + hd*DK;
      #pragma unroll
      for (int mt = 0; mt < 2; ++mt){
        #pragma unroll
        for (int g4 = 0; g4 < 4; ++g4){
          const f32x16& a = mt ? acc1 : acc0;
          const f32x4 o = *(const f32x4*)(cr + mt*64 + g4*16);
          const unsigned int u0 = cvtpk(a[4*g4+0]*f0 + o[0]*f1, a[4*g4+1]*f0 + o[1]*f1);
          const unsigned int u1 = cvtpk(a[4*g4+2]*f0 + o[2]*f1, a[4*g4+3]*f0 + o[3]*f1);
          *(unsigned long long*)(orow + mt*32 + g4*8 + hl*4) =
              (unsigned long long)u0 | ((unsigned long long)u1 << 32);
        }
      }
    }
  }
}

// ============================================================
// launch
// ============================================================
extern "C" void kernel_launch(void* const* d_in, const int* in_sizes, int n_in,
                              void* d_out, int out_size, void* d_ws, size_t ws_size,
                              hipStream_t stream)
{
  (void)in_sizes; (void)n_in; (void)out_size;
  const float* x  = (const float*)d_in[0];
  const float* wq = (const float*)d_in[1];
  const float* wk = (const float*)d_in[2];
  const float* wv = (const float*)d_in[3];
  const float* wo = (const float*)d_in[4];
  const int* pos  = (const int*)d_in[5];
  float* out = (float*)d_out;

  // workspace layout (bytes); Ab (attn out) aliases xb (x no longer needed)
  if (ws_size < 92800000u) return;   // need ~88.5 MB
  char* ws = (char*)d_ws;
  unsigned short* xb = (unsigned short*)(ws);                 // 16 MB (also Ab)
  unsigned short* wb = (unsigned short*)(ws + 16777216);      //  8 MB (Wq|Wk|Wv|Wo)
  unsigned short* Qh = (unsigned short*)(ws + 25165824);      // 16 MB [b][h][s][d]
  unsigned short* Kh = (unsigned short*)(ws + 41943040);      // 16 MB
  unsigned short* Vt = (unsigned short*)(ws + 75497472);      // 16 MB [b][h][d][s]
  float* tab         = (float*)(ws + 92274688);               // 512 KB

  k_tables  <<<256, 256, 0, stream>>>(pos, tab);
  k_convert <<<12288, 256, 0, stream>>>(x, wq, wk, wv, wo, xb, wb);
  k_gemm<0> <<<dim3(32, 8, 3), 512, 0, stream>>>(xb, wb, Qh, Kh, Vt, nullptr, tab);
  k_attn    <<<dim3(8, 64), 512, 0, stream>>>(Qh, Kh, Vt, xb);
  k_gemm<1> <<<dim3(32, 8, 1), 512, 0, stream>>>(xb, wb + 3*NW, nullptr, nullptr,
                                                 nullptr, out, nullptr);
}